// Round 3
// baseline (423.527 us; speedup 1.0000x reference)
//
#include <hip/hip_runtime.h>

// One block per image (8192 = N*B images), 256 threads. All fp32.
// LDS layouts padded/transposed for conflict-free vector reads.
__global__ __launch_bounds__(256) void cnn_kernel(
    const float* __restrict__ seq,
    const float* __restrict__ w1g, const float* __restrict__ b1g,
    const float* __restrict__ w2g, const float* __restrict__ b2g,
    const float* __restrict__ w3g, const float* __restrict__ b3g,
    const float* __restrict__ wdg, const float* __restrict__ bdg,
    float* __restrict__ out, float* __restrict__ g_ws)
{
    __shared__ __align__(16) float s_img[28 * 28];
    __shared__ __align__(16) float s_p1[8][13][14];   // row-padded 13->14 (float2 aligned)
    __shared__ __align__(16) float s_p2[16][5][8];    // row-padded 5->8 (float4 aligned)
    __shared__ float s_p3[32];
    __shared__ float s_logit[10];
    __shared__ float s_prob[10];
    __shared__ float s_w1[8][9];
    __shared__ float s_b1[8];
    __shared__ float s_w2p[16][97];    // per-c stride 97 (odd) -> bank spread
    __shared__ float s_b2[16];
    __shared__ float s_w3p[32][145];   // per-c stride 145 (odd) -> bank spread
    __shared__ float s_b3[32];
    __shared__ float s_wdt[320];       // transposed: [c2][j]
    __shared__ float s_bd[10];

    const int tid = threadIdx.x;
    const int m   = blockIdx.x;        // image id = n*256 + b, n = t*4 + d
    const int n   = m >> 8;
    const int b   = m & 255;
    const int t   = n >> 2;
    const int d   = n & 3;

    // ---- staging
    const float4* src4 = (const float4*)(seq + (((size_t)b * 8 + t) * 4 + d) * 784);
    if (tid < 196) ((float4*)s_img)[tid] = src4[tid];
    for (int i = tid; i < 72;   i += 256) (&s_w1[0][0])[i] = w1g[i];
    for (int i = tid; i < 1152; i += 256) { int c = i / 72;  s_w2p[c][i - c * 72]  = w2g[i]; }
    for (int i = tid; i < 4608; i += 256) { int c = i / 144; s_w3p[c][i - c * 144] = w3g[i]; }
    for (int i = tid; i < 320;  i += 256) { int j = i >> 5; int c2 = i & 31; s_wdt[c2 * 10 + j] = wdg[i]; }
    if (tid < 8)  s_b1[tid] = b1g[tid];
    if (tid < 16) s_b2[tid] = b2g[tid];
    if (tid < 32) s_b3[tid] = b3g[tid];
    if (tid < 10) s_bd[tid] = bdg[tid];
    __syncthreads();

    // ---- stage 1: conv1(1->8) + relu + pool2 -> (8,13,13). thread=(c,y), sliding float4 window.
    if (tid < 104) {
        const int c = tid / 13, y = tid - c * 13;
        float w[9];
        #pragma unroll
        for (int k = 0; k < 9; k++) w[k] = s_w1[c][k];
        const float bias = s_b1[c];
        const float* base = &s_img[2 * y * 28];
        float4 cur[4], nxt[4];
        #pragma unroll
        for (int i = 0; i < 4; i++) cur[i] = *(const float4*)(base + i * 28);
        float* prow = &s_p1[c][y][0];
        #pragma unroll
        for (int mm = 0; mm < 6; mm++) {
            #pragma unroll
            for (int i = 0; i < 4; i++) nxt[i] = *(const float4*)(base + i * 28 + 4 * mm + 4);
            float a[4][6];
            #pragma unroll
            for (int i = 0; i < 4; i++) {
                a[i][0] = cur[i].x; a[i][1] = cur[i].y; a[i][2] = cur[i].z; a[i][3] = cur[i].w;
                a[i][4] = nxt[i].x; a[i][5] = nxt[i].y;
            }
            float o[2];
            #pragma unroll
            for (int h = 0; h < 2; h++) {          // pooled x = 2mm+h, conv cols local 2h,2h+1
                float acc = 0.f;
                #pragma unroll
                for (int rr = 0; rr < 2; rr++)
                    #pragma unroll
                    for (int cc = 0; cc < 2; cc++) {
                        float v = bias;
                        #pragma unroll
                        for (int di = 0; di < 3; di++)
                            #pragma unroll
                            for (int dj = 0; dj < 3; dj++)
                                v += a[rr + di][2 * h + cc + dj] * w[di * 3 + dj];
                        acc += fmaxf(v, 0.f);
                    }
                o[h] = 0.25f * acc;
            }
            *(float2*)(prow + 2 * mm) = make_float2(o[0], o[1]);
            #pragma unroll
            for (int i = 0; i < 4; i++) cur[i] = nxt[i];
        }
        {   // pooled x = 12: input cols 24..27 in cur
            float a[4][4];
            #pragma unroll
            for (int i = 0; i < 4; i++) {
                a[i][0] = cur[i].x; a[i][1] = cur[i].y; a[i][2] = cur[i].z; a[i][3] = cur[i].w;
            }
            float acc = 0.f;
            #pragma unroll
            for (int rr = 0; rr < 2; rr++)
                #pragma unroll
                for (int cc = 0; cc < 2; cc++) {
                    float v = bias;
                    #pragma unroll
                    for (int di = 0; di < 3; di++)
                        #pragma unroll
                        for (int dj = 0; dj < 3; dj++)
                            v += a[rr + di][cc + dj] * w[di * 3 + dj];
                    acc += fmaxf(v, 0.f);
                }
            prow[12] = 0.25f * acc;
        }
    }
    __syncthreads();

    // ---- stage 2: conv2(8->16) + relu + pool2 -> (16,5,5). thread=(c,y,mm): mm<2 -> pair, mm=2 -> x=4.
    if (tid < 240) {
        const int c   = tid / 15;
        const int rem = tid - c * 15;
        const int y   = rem / 3;
        const int mm  = rem - y * 3;
        const float bias = s_b2[c];
        const float* wb  = &s_w2p[c][0];
        const int r0 = 2 * y;
        const int colbase = 4 * mm;            // mm=2 -> cols 8..11
        float v[2][4];
        #pragma unroll
        for (int rr = 0; rr < 2; rr++)
            #pragma unroll
            for (int cc = 0; cc < 4; cc++) v[rr][cc] = bias;
        for (int ic = 0; ic < 8; ic++) {
            float a[4][6];
            #pragma unroll
            for (int i = 0; i < 4; i++) {
                const float* rp = &s_p1[ic][r0 + i][colbase];
                float2 q0 = *(const float2*)(rp);
                float2 q1 = *(const float2*)(rp + 2);
                a[i][0] = q0.x; a[i][1] = q0.y; a[i][2] = q1.x; a[i][3] = q1.y;
                if (mm < 2) {
                    float2 q2 = *(const float2*)(rp + 4);
                    a[i][4] = q2.x; a[i][5] = q2.y;
                }
            }
            float w[9];
            #pragma unroll
            for (int k = 0; k < 9; k++) w[k] = wb[ic * 9 + k];
            #pragma unroll
            for (int di = 0; di < 3; di++)
                #pragma unroll
                for (int dj = 0; dj < 3; dj++) {
                    const float wk = w[di * 3 + dj];
                    #pragma unroll
                    for (int rr = 0; rr < 2; rr++) {
                        v[rr][0] += a[rr + di][0 + dj] * wk;
                        v[rr][1] += a[rr + di][1 + dj] * wk;
                        if (mm < 2) {
                            v[rr][2] += a[rr + di][2 + dj] * wk;
                            v[rr][3] += a[rr + di][3 + dj] * wk;
                        }
                    }
                }
        }
        if (mm < 2) {
            float o0 = 0.25f * (fmaxf(v[0][0], 0.f) + fmaxf(v[0][1], 0.f) +
                                fmaxf(v[1][0], 0.f) + fmaxf(v[1][1], 0.f));
            float o1 = 0.25f * (fmaxf(v[0][2], 0.f) + fmaxf(v[0][3], 0.f) +
                                fmaxf(v[1][2], 0.f) + fmaxf(v[1][3], 0.f));
            *(float2*)&s_p2[c][y][2 * mm] = make_float2(o0, o1);
        } else {
            s_p2[c][y][4] = 0.25f * (fmaxf(v[0][0], 0.f) + fmaxf(v[0][1], 0.f) +
                                     fmaxf(v[1][0], 0.f) + fmaxf(v[1][1], 0.f));
        }
    }
    __syncthreads();

    // ---- stage 3: conv3(16->32) + relu + pool -> (32,). thread = out channel c.
    if (tid < 32) {
        const int c = tid;
        const float bias = s_b3[c];
        float acc[2][2] = {{bias, bias}, {bias, bias}};
        const float* wb = &s_w3p[c][0];
        for (int ic = 0; ic < 16; ic++) {
            float a[4][4];
            #pragma unroll
            for (int i = 0; i < 4; i++) {
                float4 r = *(const float4*)&s_p2[ic][i][0];    // broadcast across lanes
                a[i][0] = r.x; a[i][1] = r.y; a[i][2] = r.z; a[i][3] = r.w;
            }
            float w[9];
            #pragma unroll
            for (int k = 0; k < 9; k++) w[k] = wb[ic * 9 + k];
            #pragma unroll
            for (int u = 0; u < 2; u++)
                #pragma unroll
                for (int vv = 0; vv < 2; vv++)
                    #pragma unroll
                    for (int di = 0; di < 3; di++)
                        #pragma unroll
                        for (int dj = 0; dj < 3; dj++)
                            acc[u][vv] += a[u + di][vv + dj] * w[di * 3 + dj];
        }
        s_p3[c] = 0.25f * (fmaxf(acc[0][0], 0.f) + fmaxf(acc[0][1], 0.f) +
                           fmaxf(acc[1][0], 0.f) + fmaxf(acc[1][1], 0.f));
    }
    __syncthreads();

    // ---- dense + softmax + guards
    if (tid < 10) {
        float acc = s_bd[tid];
        #pragma unroll
        for (int c2 = 0; c2 < 32; c2++) acc += s_p3[c2] * s_wdt[c2 * 10 + tid];
        s_logit[tid] = acc;
    }
    __syncthreads();
    if (tid < 10) {
        float mx = s_logit[0];
        #pragma unroll
        for (int k = 1; k < 10; k++) mx = fmaxf(mx, s_logit[k]);
        float ssum = 0.f;
        #pragma unroll
        for (int k = 0; k < 10; k++) ssum += __expf(s_logit[k] - mx);
        float p = __expf(s_logit[tid] - mx) / ssum;
        s_prob[tid] = p;
        out[(size_t)m * 10 + tid] = p;                 // all_cnn_preds (N,B,10)
    }
    __syncthreads();
    if (tid < 6) {
        // rules: [p8, p4+p6, p0+p2, p7+p9, p5, p1+p3]
        int ia = (0x157048 >> (tid * 4)) & 0xF;
        int ib = (0x3F926F >> (tid * 4)) & 0xF;
        float gv = s_prob[ia] + (ib < 10 ? s_prob[ib] : 0.f);
        out[81920 + (size_t)m * 6 + tid] = gv;         // all_guard_preds (N,B,6)
        g_ws[(size_t)m * 6 + tid] = gv;                // scratch for recurrence
    }
}

// 8 blocks x 320 threads; thread = (batch-in-block bb, state j). M column in registers.
__global__ __launch_bounds__(320) void sfa_kernel(
    const float* __restrict__ trans,
    const float* __restrict__ g_ws,
    float* __restrict__ out)
{
    __shared__ float M[6][10][10];
    __shared__ float st_s[32][10];
    __shared__ float g_s[32][6];
    const int tid = threadIdx.x;

    if (tid < 54) {
        int r = tid / 9, i = tid - r * 9;
        const float* row = trans + (size_t)(r * 9 + i) * 10;
        float x[10], mx = -1e30f;
        #pragma unroll
        for (int j = 0; j < 10; j++) { x[j] = 10.f * row[j]; mx = fmaxf(mx, x[j]); }
        float s = 0.f;
        #pragma unroll
        for (int j = 0; j < 10; j++) { x[j] = __expf(x[j] - mx); s += x[j]; }
        float inv = 1.f / s;
        #pragma unroll
        for (int j = 0; j < 10; j++) M[r][i][j] = x[j] * inv;
    }
    __syncthreads();

    const int bb = tid / 10;
    const int j  = tid - bb * 10;
    float Mreg[54];                       // M[r][i][j] for own j, i<9 (row 9 = identity, analytic)
    #pragma unroll
    for (int r = 0; r < 6; r++)
        #pragma unroll
        for (int i = 0; i < 9; i++) Mreg[r * 9 + i] = M[r][i][j];

    const int b = blockIdx.x * 32 + bb;
    float stj = (j == 0) ? 1.f : 0.f;
    st_s[bb][j] = stj;
    const int gbase0 = blockIdx.x * 192;

    for (int n = 0; n < 32; n++) {
        if (tid < 192) ((float*)g_s)[tid] = g_ws[(size_t)n * 1536 + gbase0 + tid];
        __syncthreads();
        float st[10];
        #pragma unroll
        for (int i = 0; i < 10; i++) st[i] = st_s[bb][i];
        float g[6], gsum = 0.f;
        #pragma unroll
        for (int r = 0; r < 6; r++) { g[r] = g_s[bb][r]; gsum += g[r]; }
        float ns = (j == 9) ? gsum * st[9] : 0.f;      // accepting row contribution
        #pragma unroll
        for (int r = 0; r < 6; r++) {
            float h = 0.f;
            #pragma unroll
            for (int i = 0; i < 9; i++) h += st[i] * Mreg[r * 9 + i];
            ns += g[r] * h;
        }
        __syncthreads();
        st_s[bb][j] = ns;
        stj = ns;
    }
    out[131072 + (size_t)b * 10 + j] = stj;            // state_final (B,10)
}

extern "C" void kernel_launch(void* const* d_in, const int* in_sizes, int n_in,
                              void* d_out, int out_size, void* d_ws, size_t ws_size,
                              hipStream_t stream) {
    const float* seq = (const float*)d_in[0];
    const float* w1  = (const float*)d_in[1];
    const float* b1  = (const float*)d_in[2];
    const float* w2  = (const float*)d_in[3];
    const float* b2  = (const float*)d_in[4];
    const float* w3  = (const float*)d_in[5];
    const float* b3  = (const float*)d_in[6];
    const float* wd  = (const float*)d_in[7];
    const float* bd  = (const float*)d_in[8];
    const float* tr  = (const float*)d_in[9];
    float* out  = (float*)d_out;
    float* g_ws = (float*)d_ws;   // 8192*6 fp32 guard scratch

    cnn_kernel<<<8192, 256, 0, stream>>>(seq, w1, b1, w2, b2, w3, b3, wd, bd, out, g_ws);
    sfa_kernel<<<8, 320, 0, stream>>>(tr, g_ws, out);
}

// Round 4
// 330.185 us; speedup vs baseline: 1.2827x; 1.2827x over previous
//
#include <hip/hip_runtime.h>

// One block per image (8192 = N*B images), 256 threads. All fp32.
// R2 work decomposition (68 VGPR, 32% occ) + widened LDS reads (float2/float4),
// padded/odd strides to kill measured bank conflicts.
__global__ __launch_bounds__(256) void cnn_kernel(
    const float* __restrict__ seq,
    const float* __restrict__ w1g, const float* __restrict__ b1g,
    const float* __restrict__ w2g, const float* __restrict__ b2g,
    const float* __restrict__ w3g, const float* __restrict__ b3g,
    const float* __restrict__ wdg, const float* __restrict__ bdg,
    float* __restrict__ out, float* __restrict__ g_ws)
{
    __shared__ __align__(16) float s_img[28 * 28];
    __shared__ __align__(16) float s_p1[8][13][14];   // rows padded 13->14 (float2-aligned)
    __shared__ __align__(16) float s_p2[16][5][8];    // rows padded 5->8  (float4-aligned)
    __shared__ float s_p3[32];
    __shared__ float s_logit[10];
    __shared__ float s_prob[10];
    __shared__ float s_w1[8][9];
    __shared__ float s_b1[8];
    __shared__ float s_w2[16][8][9];
    __shared__ float s_b2[16];
    __shared__ float s_w3p[32][145];   // odd stride -> c*145 mod 32 spreads banks
    __shared__ float s_b3[32];
    __shared__ float s_wdt[320];       // transposed: [c2][j]
    __shared__ float s_bd[10];

    const int tid = threadIdx.x;
    const int m   = blockIdx.x;        // image id = n*256 + b, n = t*4 + d
    const int n   = m >> 8;
    const int b   = m & 255;
    const int t   = n >> 2;
    const int d   = n & 3;

    // ---- staging
    const float4* src4 = (const float4*)(seq + (((size_t)b * 8 + t) * 4 + d) * 784);
    if (tid < 196) ((float4*)s_img)[tid] = src4[tid];
    for (int i = tid; i < 72;   i += 256) (&s_w1[0][0])[i]    = w1g[i];
    for (int i = tid; i < 1152; i += 256) (&s_w2[0][0][0])[i] = w2g[i];
    for (int i = tid; i < 4608; i += 256) { int c = i / 144; s_w3p[c][i - c * 144] = w3g[i]; }
    for (int i = tid; i < 320;  i += 256) { int j = i >> 5; int c2 = i & 31; s_wdt[c2 * 10 + j] = wdg[i]; }
    if (tid < 8)  s_b1[tid] = b1g[tid];
    if (tid < 16) s_b2[tid] = b2g[tid];
    if (tid < 32) s_b3[tid] = b3g[tid];
    if (tid < 10) s_bd[tid] = bdg[tid];
    __syncthreads();

    // ---- stage 1: conv1(1->8) + relu + pool2 -> (8,13,13). item = (c,y,x) pooled output.
    for (int idx = tid; idx < 8 * 169; idx += 256) {
        int c   = idx / 169;
        int rem = idx - c * 169;
        int y   = rem / 13;
        int x   = rem - y * 13;
        int r0 = 2 * y, c0 = 2 * x;                 // c0 even -> float2-aligned
        float p[4][4];
        #pragma unroll
        for (int i = 0; i < 4; i++) {
            const float* rp = &s_img[(r0 + i) * 28 + c0];
            float2 q0 = *(const float2*)(rp);
            float2 q1 = *(const float2*)(rp + 2);
            p[i][0] = q0.x; p[i][1] = q0.y; p[i][2] = q1.x; p[i][3] = q1.y;
        }
        const float* W = s_w1[c];
        const float bias = s_b1[c];
        float acc = 0.f;
        #pragma unroll
        for (int dy = 0; dy < 2; dy++)
            #pragma unroll
            for (int dx = 0; dx < 2; dx++) {
                float v = bias;
                #pragma unroll
                for (int i = 0; i < 3; i++)
                    #pragma unroll
                    for (int j = 0; j < 3; j++)
                        v += p[dy + i][dx + j] * W[i * 3 + j];
                acc += fmaxf(v, 0.f);
            }
        s_p1[c][y][x] = 0.25f * acc;
    }
    __syncthreads();

    // ---- stage 2: conv2(8->16) + relu + pool2 -> (16,5,5). item = (c,y,x) pooled output.
    for (int idx = tid; idx < 16 * 25; idx += 256) {
        int c   = idx / 25;
        int rem = idx - c * 25;
        int y   = rem / 5;
        int x   = rem - y * 5;
        int r0 = 2 * y, c0 = 2 * x;                 // c0 even, row stride 14 -> aligned
        const float bias = s_b2[c];
        float v00 = bias, v01 = bias, v10 = bias, v11 = bias;
        for (int ic = 0; ic < 8; ic++) {
            float p[4][4];
            #pragma unroll
            for (int i = 0; i < 4; i++) {
                const float* rp = &s_p1[ic][r0 + i][c0];
                float2 q0 = *(const float2*)(rp);
                float2 q1 = *(const float2*)(rp + 2);
                p[i][0] = q0.x; p[i][1] = q0.y; p[i][2] = q1.x; p[i][3] = q1.y;
            }
            const float* W = s_w2[c][ic];
            float w[9];
            #pragma unroll
            for (int k = 0; k < 9; k++) w[k] = W[k];
            #pragma unroll
            for (int i = 0; i < 3; i++)
                #pragma unroll
                for (int j = 0; j < 3; j++) {
                    float wk = w[i * 3 + j];
                    v00 += p[i    ][j    ] * wk;
                    v01 += p[i    ][j + 1] * wk;
                    v10 += p[i + 1][j    ] * wk;
                    v11 += p[i + 1][j + 1] * wk;
                }
        }
        s_p2[c][y][x] = 0.25f * (fmaxf(v00, 0.f) + fmaxf(v01, 0.f) +
                                 fmaxf(v10, 0.f) + fmaxf(v11, 0.f));
    }
    __syncthreads();

    // ---- stage 3: conv3(16->32) + relu at 2x2 window; thread = (c,u,v), 128 threads.
    if (tid < 128) {
        int c = tid >> 2;
        int u = (tid >> 1) & 1;
        int v = tid & 1;
        float acc = s_b3[c];
        const float* wb = &s_w3p[c][0];
        for (int ic = 0; ic < 16; ic++) {
            float4 r0 = *(const float4*)&s_p2[ic][u    ][0];   // cols 0..3 cover v..v+2
            float4 r1 = *(const float4*)&s_p2[ic][u + 1][0];
            float4 r2 = *(const float4*)&s_p2[ic][u + 2][0];
            float a[3][4];
            a[0][0] = r0.x; a[0][1] = r0.y; a[0][2] = r0.z; a[0][3] = r0.w;
            a[1][0] = r1.x; a[1][1] = r1.y; a[1][2] = r1.z; a[1][3] = r1.w;
            a[2][0] = r2.x; a[2][1] = r2.y; a[2][2] = r2.z; a[2][3] = r2.w;
            const float* W = wb + ic * 9;
            #pragma unroll
            for (int i = 0; i < 3; i++)
                #pragma unroll
                for (int j = 0; j < 3; j++)
                    acc += a[i][v + j] * W[i * 3 + j];
        }
        // pool over the 2x2 relu'd window via LDS staging in s_p2 scratch? use shfl-free path:
        // write relu value, reduce below.
        s_p3[c] = 0.f;  // init by first quad lane later; use atomic-free two-phase:
        // store per-(u,v) into s_logit area? simplest: reuse s_p2[0] scratch is unsafe (still needed? no)
        // stash in s_w3p tail (unused slot 144 per row is free, need 4 per c): use s_w3p[c][144] impossible for 4.
        // Use dedicated array below instead.
        ((float*)s_wdt)[0] = ((float*)s_wdt)[0]; // no-op to keep structure clear
        __shared__ float s_c3[32][4];
        s_c3[c][(u << 1) | v] = fmaxf(acc, 0.f);
        __syncthreads();
        if (tid < 32)
            s_p3[tid] = 0.25f * (s_c3[tid][0] + s_c3[tid][1] + s_c3[tid][2] + s_c3[tid][3]);
    } else {
        __syncthreads();
    }
    __syncthreads();

    // ---- dense + softmax + guards
    if (tid < 10) {
        float acc = s_bd[tid];
        #pragma unroll
        for (int c2 = 0; c2 < 32; c2++) acc += s_p3[c2] * s_wdt[c2 * 10 + tid];
        s_logit[tid] = acc;
    }
    __syncthreads();
    if (tid < 10) {
        float mx = s_logit[0];
        #pragma unroll
        for (int k = 1; k < 10; k++) mx = fmaxf(mx, s_logit[k]);
        float ssum = 0.f;
        #pragma unroll
        for (int k = 0; k < 10; k++) ssum += __expf(s_logit[k] - mx);
        float p = __expf(s_logit[tid] - mx) / ssum;
        s_prob[tid] = p;
        out[(size_t)m * 10 + tid] = p;                 // all_cnn_preds (N,B,10)
    }
    __syncthreads();
    if (tid < 6) {
        // rules: [p8, p4+p6, p0+p2, p7+p9, p5, p1+p3]
        int ia = (0x157048 >> (tid * 4)) & 0xF;
        int ib = (0x3F926F >> (tid * 4)) & 0xF;
        float gv = s_prob[ia] + (ib < 10 ? s_prob[ib] : 0.f);
        out[81920 + (size_t)m * 6 + tid] = gv;         // all_guard_preds (N,B,6)
        g_ws[(size_t)m * 6 + tid] = gv;                // scratch for recurrence
    }
}

// 11 blocks x 256 threads. lane = bb*10 + j inside a wave (6 batches/wave, lanes 60-63 idle).
// M column in 54 registers; state exchange via __shfl — ZERO barriers in the 32-step loop.
__global__ __launch_bounds__(256) void sfa_kernel(
    const float* __restrict__ trans,
    const float* __restrict__ g_ws,
    float* __restrict__ out)
{
    __shared__ float M[600];           // [r][i][j]
    const int tid  = threadIdx.x;
    const int lane = tid & 63;
    const int wv   = tid >> 6;

    if (tid < 54) {
        int r = tid / 9, i = tid - r * 9;
        const float* row = trans + (size_t)(r * 9 + i) * 10;
        float x[10], mx = -1e30f;
        #pragma unroll
        for (int j = 0; j < 10; j++) { x[j] = 10.f * row[j]; mx = fmaxf(mx, x[j]); }
        float s = 0.f;
        #pragma unroll
        for (int j = 0; j < 10; j++) { x[j] = __expf(x[j] - mx); s += x[j]; }
        float inv = 1.f / s;
        #pragma unroll
        for (int j = 0; j < 10; j++) M[(r * 9 + i) * 10 + j] = x[j] * inv;
    }
    __syncthreads();

    const int bb    = lane / 10;                    // batch-in-wave, 0..6 (6 invalid)
    const int j     = lane - bb * 10;
    const int base  = bb * 10;                      // first lane of this batch group
    const bool ok   = (bb < 6);
    int batch = blockIdx.x * 24 + wv * 6 + bb;
    const bool live = ok && (batch < 256);
    if (!live) batch = 0;                           // clamp for safe loads

    float Mreg[54];
    #pragma unroll
    for (int k = 0; k < 54; k++) Mreg[k] = M[k * 10 + j];

    float stj = (j == 0) ? 1.f : 0.f;

    for (int nn = 0; nn < 32; nn++) {
        const float* gp = g_ws + ((size_t)nn * 256 + batch) * 6;
        float2 ga = *(const float2*)(gp);
        float2 gb = *(const float2*)(gp + 2);
        float2 gc = *(const float2*)(gp + 4);
        float g[6] = {ga.x, ga.y, gb.x, gb.y, gc.x, gc.y};

        float st[10];
        #pragma unroll
        for (int i = 0; i < 10; i++) st[i] = __shfl(stj, base + i, 64);

        float gsum = g[0] + g[1] + g[2] + g[3] + g[4] + g[5];
        float ns = (j == 9) ? gsum * st[9] : 0.f;   // accepting row
        #pragma unroll
        for (int r = 0; r < 6; r++) {
            float h = 0.f;
            #pragma unroll
            for (int i = 0; i < 9; i++) h += st[i] * Mreg[r * 9 + i];
            ns += g[r] * h;
        }
        stj = ns;
    }
    if (live) out[131072 + (size_t)batch * 10 + j] = stj;   // state_final (B,10)
}

extern "C" void kernel_launch(void* const* d_in, const int* in_sizes, int n_in,
                              void* d_out, int out_size, void* d_ws, size_t ws_size,
                              hipStream_t stream) {
    const float* seq = (const float*)d_in[0];
    const float* w1  = (const float*)d_in[1];
    const float* b1  = (const float*)d_in[2];
    const float* w2  = (const float*)d_in[3];
    const float* b2  = (const float*)d_in[4];
    const float* w3  = (const float*)d_in[5];
    const float* b3  = (const float*)d_in[6];
    const float* wd  = (const float*)d_in[7];
    const float* bd  = (const float*)d_in[8];
    const float* tr  = (const float*)d_in[9];
    float* out  = (float*)d_out;
    float* g_ws = (float*)d_ws;   // 8192*6 fp32 guard scratch

    cnn_kernel<<<8192, 256, 0, stream>>>(seq, w1, b1, w2, b2, w3, b3, wd, bd, out, g_ws);
    sfa_kernel<<<11, 256, 0, stream>>>(tr, g_ws, out);
}

// Round 5
// 219.056 us; speedup vs baseline: 1.9334x; 1.5073x over previous
//
#include <hip/hip_runtime.h>

// One block per image (8192 = N*B images), 256 threads. All fp32.
// R2's exact scalar instruction structure; activations stored column-parity
// DE-INTERLEAVED (row = [even cols | odd cols]) so pool-fused conv reads are
// unit-stride across lanes -> conflict-free. w3 odd-stride, dense transposed.
__global__ __launch_bounds__(256) void cnn_kernel(
    const float* __restrict__ seq,
    const float* __restrict__ w1g, const float* __restrict__ b1g,
    const float* __restrict__ w2g, const float* __restrict__ b2g,
    const float* __restrict__ w3g, const float* __restrict__ b3g,
    const float* __restrict__ wdg, const float* __restrict__ bdg,
    float* __restrict__ out, float* __restrict__ g_ws)
{
    __shared__ __align__(16) float s_img2[28][28];  // row: [0..13]=cols 0,2,..26; [14..27]=cols 1,3,..27
    __shared__ __align__(16) float s_p1[8][13][14]; // row: [0..6]=cols 0,2,..12; [7..13]=cols 1,3,..11
    __shared__ __align__(16) float s_p2[16][5][6];  // plain, padded 5->6
    __shared__ float s_c3[32][4];
    __shared__ float s_p3[32];
    __shared__ float s_logit[10];
    __shared__ float s_prob[10];
    __shared__ float s_w1[8][9];
    __shared__ float s_b1[8];
    __shared__ float s_w2[16][8][9];
    __shared__ float s_b2[16];
    __shared__ float s_w3p[32][145];   // odd stride spreads banks (144 == 16 mod 32 was 8-way)
    __shared__ float s_b3[32];
    __shared__ float s_wdt[320];       // transposed: [c2][j]
    __shared__ float s_bd[10];

    const int tid = threadIdx.x;
    const int m   = blockIdx.x;        // image id = n*256 + b, n = t*4 + d
    const int n   = m >> 8;
    const int b   = m & 255;
    const int t   = n >> 2;
    const int d   = n & 3;

    // ---- staging (image de-interleaved by column parity)
    const float4* src4 = (const float4*)(seq + (((size_t)b * 8 + t) * 4 + d) * 784);
    if (tid < 196) {
        float4 v = src4[tid];
        int flat = tid * 4;
        int r = flat / 28;
        int cb = flat - r * 28;        // multiple of 4
        int e = cb >> 1;               // even: e, e+1 ; odd: e, e+1
        *(float2*)&s_img2[r][e]      = make_float2(v.x, v.z);
        *(float2*)&s_img2[r][14 + e] = make_float2(v.y, v.w);
    }
    for (int i = tid; i < 72;   i += 256) (&s_w1[0][0])[i]    = w1g[i];
    for (int i = tid; i < 1152; i += 256) (&s_w2[0][0][0])[i] = w2g[i];
    for (int i = tid; i < 4608; i += 256) { int c = i / 144; s_w3p[c][i - c * 144] = w3g[i]; }
    for (int i = tid; i < 320;  i += 256) { int j = i >> 5; int c2 = i & 31; s_wdt[c2 * 10 + j] = wdg[i]; }
    if (tid < 8)  s_b1[tid] = b1g[tid];
    if (tid < 16) s_b2[tid] = b2g[tid];
    if (tid < 32) s_b3[tid] = b3g[tid];
    if (tid < 10) s_bd[tid] = bdg[tid];
    __syncthreads();

    // ---- stage 1: conv1(1->8) + relu + pool2 -> (8,13,13). item = (c,y,x) pooled output.
    for (int idx = tid; idx < 8 * 169; idx += 256) {
        int c   = idx / 169;
        int rem = idx - c * 169;
        int y   = rem / 13;
        int x   = rem - y * 13;
        int r0 = 2 * y;
        float p[4][4];
        #pragma unroll
        for (int i = 0; i < 4; i++) {
            const float* rp = &s_img2[r0 + i][0];
            p[i][0] = rp[x];            // col 2x
            p[i][1] = rp[14 + x];       // col 2x+1
            p[i][2] = rp[x + 1];        // col 2x+2
            p[i][3] = rp[15 + x];       // col 2x+3
        }
        const float* W = s_w1[c];
        const float bias = s_b1[c];
        float acc = 0.f;
        #pragma unroll
        for (int dy = 0; dy < 2; dy++)
            #pragma unroll
            for (int dx = 0; dx < 2; dx++) {
                float v = bias;
                #pragma unroll
                for (int i = 0; i < 3; i++)
                    #pragma unroll
                    for (int j = 0; j < 3; j++)
                        v += p[dy + i][dx + j] * W[i * 3 + j];
                acc += fmaxf(v, 0.f);
            }
        // de-interleaved write: even x -> slot x/2, odd x -> slot 7 + x/2 (banks distinct)
        s_p1[c][y][(x >> 1) + 7 * (x & 1)] = 0.25f * acc;
    }
    __syncthreads();

    // ---- stage 2: conv2(8->16) + relu + pool2 -> (16,5,5). item = (c,y,x) pooled output.
    for (int idx = tid; idx < 16 * 25; idx += 256) {
        int c   = idx / 25;
        int rem = idx - c * 25;
        int y   = rem / 5;
        int x   = rem - y * 5;
        int r0 = 2 * y;
        const float bias = s_b2[c];
        float v00 = bias, v01 = bias, v10 = bias, v11 = bias;
        for (int ic = 0; ic < 8; ic++) {
            float p[4][4];
            #pragma unroll
            for (int i = 0; i < 4; i++) {
                const float* rp = &s_p1[ic][r0 + i][0];
                p[i][0] = rp[x];        // col 2x
                p[i][1] = rp[7 + x];    // col 2x+1
                p[i][2] = rp[x + 1];    // col 2x+2
                p[i][3] = rp[8 + x];    // col 2x+3
            }
            const float* W = s_w2[c][ic];
            float w[9];
            #pragma unroll
            for (int k = 0; k < 9; k++) w[k] = W[k];
            #pragma unroll
            for (int i = 0; i < 3; i++)
                #pragma unroll
                for (int j = 0; j < 3; j++) {
                    float wk = w[i * 3 + j];
                    v00 += p[i    ][j    ] * wk;
                    v01 += p[i    ][j + 1] * wk;
                    v10 += p[i + 1][j    ] * wk;
                    v11 += p[i + 1][j + 1] * wk;
                }
        }
        s_p2[c][y][x] = 0.25f * (fmaxf(v00, 0.f) + fmaxf(v01, 0.f) +
                                 fmaxf(v10, 0.f) + fmaxf(v11, 0.f));
    }
    __syncthreads();

    // ---- stage 3: conv3(16->32) + relu at 2x2 window; thread = (c,u,v), 128 threads.
    if (tid < 128) {
        int c = tid >> 2;
        int u = (tid >> 1) & 1;
        int v = tid & 1;
        float acc = s_b3[c];
        const float* wb = &s_w3p[c][0];
        for (int ic = 0; ic < 16; ic++) {
            const float* W = wb + ic * 9;
            #pragma unroll
            for (int i = 0; i < 3; i++)
                #pragma unroll
                for (int j = 0; j < 3; j++)
                    acc += s_p2[ic][u + i][v + j] * W[i * 3 + j];
        }
        s_c3[c][(u << 1) | v] = fmaxf(acc, 0.f);
    }
    __syncthreads();
    if (tid < 32)
        s_p3[tid] = 0.25f * (s_c3[tid][0] + s_c3[tid][1] + s_c3[tid][2] + s_c3[tid][3]);
    __syncthreads();

    // ---- dense + softmax + guards
    if (tid < 10) {
        float acc = s_bd[tid];
        #pragma unroll
        for (int c2 = 0; c2 < 32; c2++) acc += s_p3[c2] * s_wdt[c2 * 10 + tid];
        s_logit[tid] = acc;
    }
    __syncthreads();
    if (tid < 10) {
        float mx = s_logit[0];
        #pragma unroll
        for (int k = 1; k < 10; k++) mx = fmaxf(mx, s_logit[k]);
        float ssum = 0.f;
        #pragma unroll
        for (int k = 0; k < 10; k++) ssum += __expf(s_logit[k] - mx);
        float p = __expf(s_logit[tid] - mx) / ssum;
        s_prob[tid] = p;
        out[(size_t)m * 10 + tid] = p;                 // all_cnn_preds (N,B,10)
    }
    __syncthreads();
    if (tid < 6) {
        // rules: [p8, p4+p6, p0+p2, p7+p9, p5, p1+p3]
        int ia = (0x157048 >> (tid * 4)) & 0xF;
        int ib = (0x3F926F >> (tid * 4)) & 0xF;
        float gv = s_prob[ia] + (ib < 10 ? s_prob[ib] : 0.f);
        out[81920 + (size_t)m * 6 + tid] = gv;         // all_guard_preds (N,B,6)
        g_ws[(size_t)m * 6 + tid] = gv;                // scratch for recurrence
    }
}

// 11 blocks x 256 threads. lane = bb*10 + j inside a wave (6 batches/wave).
// M column in 54 registers; state exchange via __shfl — zero barriers in the loop.
__global__ __launch_bounds__(256) void sfa_kernel(
    const float* __restrict__ trans,
    const float* __restrict__ g_ws,
    float* __restrict__ out)
{
    __shared__ float M[600];           // [r][i][j]
    const int tid  = threadIdx.x;
    const int lane = tid & 63;
    const int wv   = tid >> 6;

    if (tid < 54) {
        int r = tid / 9, i = tid - r * 9;
        const float* row = trans + (size_t)(r * 9 + i) * 10;
        float x[10], mx = -1e30f;
        #pragma unroll
        for (int j = 0; j < 10; j++) { x[j] = 10.f * row[j]; mx = fmaxf(mx, x[j]); }
        float s = 0.f;
        #pragma unroll
        for (int j = 0; j < 10; j++) { x[j] = __expf(x[j] - mx); s += x[j]; }
        float inv = 1.f / s;
        #pragma unroll
        for (int j = 0; j < 10; j++) M[(r * 9 + i) * 10 + j] = x[j] * inv;
    }
    __syncthreads();

    const int bb    = lane / 10;                    // batch-in-wave, 0..6 (6 invalid)
    const int j     = lane - bb * 10;
    const int base  = bb * 10;
    const bool ok   = (bb < 6);
    int batch = blockIdx.x * 24 + wv * 6 + bb;
    const bool live = ok && (batch < 256);
    if (!live) batch = 0;

    float Mreg[54];
    #pragma unroll
    for (int k = 0; k < 54; k++) Mreg[k] = M[k * 10 + j];

    float stj = (j == 0) ? 1.f : 0.f;

    for (int nn = 0; nn < 32; nn++) {
        const float* gp = g_ws + ((size_t)nn * 256 + batch) * 6;
        float2 ga = *(const float2*)(gp);
        float2 gb = *(const float2*)(gp + 2);
        float2 gc = *(const float2*)(gp + 4);
        float g[6] = {ga.x, ga.y, gb.x, gb.y, gc.x, gc.y};

        float st[10];
        #pragma unroll
        for (int i = 0; i < 10; i++) st[i] = __shfl(stj, base + i, 64);

        float gsum = g[0] + g[1] + g[2] + g[3] + g[4] + g[5];
        float ns = (j == 9) ? gsum * st[9] : 0.f;   // accepting row
        #pragma unroll
        for (int r = 0; r < 6; r++) {
            float h = 0.f;
            #pragma unroll
            for (int i = 0; i < 9; i++) h += st[i] * Mreg[r * 9 + i];
            ns += g[r] * h;
        }
        stj = ns;
    }
    if (live) out[131072 + (size_t)batch * 10 + j] = stj;   // state_final (B,10)
}

extern "C" void kernel_launch(void* const* d_in, const int* in_sizes, int n_in,
                              void* d_out, int out_size, void* d_ws, size_t ws_size,
                              hipStream_t stream) {
    const float* seq = (const float*)d_in[0];
    const float* w1  = (const float*)d_in[1];
    const float* b1  = (const float*)d_in[2];
    const float* w2  = (const float*)d_in[3];
    const float* b2  = (const float*)d_in[4];
    const float* w3  = (const float*)d_in[5];
    const float* b3  = (const float*)d_in[6];
    const float* wd  = (const float*)d_in[7];
    const float* bd  = (const float*)d_in[8];
    const float* tr  = (const float*)d_in[9];
    float* out  = (float*)d_out;
    float* g_ws = (float*)d_ws;   // 8192*6 fp32 guard scratch

    cnn_kernel<<<8192, 256, 0, stream>>>(seq, w1, b1, w2, b2, w3, b3, wd, bd, out, g_ws);
    sfa_kernel<<<11, 256, 0, stream>>>(tr, g_ws, out);
}

// Round 6
// 191.240 us; speedup vs baseline: 2.2146x; 1.1455x over previous
//
#include <hip/hip_runtime.h>

// One block per image (8192 = N*B images), 256 threads. All fp32.
// Key facts exploited:
//  - floor-mode pooling => conv3 uses only p2[0..3][0..3]; conv2 uses only p1[0..9][0..9]
//    => stage1: 800 items (not 1352), stage2: 256 items (not 400).
//  - ic-fastest LDS layouts => stage2/3 read 4 channels per ds_read_b128.
__global__ __launch_bounds__(256) void cnn_kernel(
    const float* __restrict__ seq,
    const float* __restrict__ w1g, const float* __restrict__ b1g,
    const float* __restrict__ w2g, const float* __restrict__ b2g,
    const float* __restrict__ w3g, const float* __restrict__ b3g,
    const float* __restrict__ wdg, const float* __restrict__ bdg,
    float* __restrict__ out, float* __restrict__ g_ws)
{
    __shared__ __align__(16) float s_img2[28][28];  // row: [0..13]=even cols, [14..27]=odd cols
    __shared__ __align__(16) float s_p1n[10][11][8];// [y][col-slot][ic]; slot=(c'>>1)+5*(c'&1); stride 11
    __shared__ __align__(16) float s_p2n[256];      // [pixel(y*4+x)][16 ic]
    __shared__ __align__(16) float s_w2n[1152];     // [k][g][c][4]: ((k*2+g)*16+c)*4+l ; ic=g*4+l
    __shared__ __align__(16) float s_w3n[4608];     // [k][g][c][4]: ((k*4+g)*32+c)*4+l ; ic=g*4+l
    __shared__ float s_w1[8][9];
    __shared__ float s_b1[8];
    __shared__ float s_b2[16];
    __shared__ float s_b3[32];
    __shared__ float s_wdt[320];                    // transposed dense: [c2][j]
    __shared__ float s_bd[10];
    __shared__ float s_c3[32][4];
    __shared__ float s_p3[32];
    __shared__ float s_logit[10];
    __shared__ float s_prob[10];

    const int tid = threadIdx.x;
    const int m   = blockIdx.x;        // image id = n*256 + b, n = t*4 + d
    const int n   = m >> 8;
    const int b   = m & 255;
    const int t   = n >> 2;
    const int d   = n & 3;

    // ---- staging
    const float4* src4 = (const float4*)(seq + (((size_t)b * 8 + t) * 4 + d) * 784);
    if (tid < 196) {
        float4 v = src4[tid];
        int flat = tid * 4;
        int r  = flat / 28;
        int cb = flat - r * 28;        // multiple of 4
        int e  = cb >> 1;
        *(float2*)&s_img2[r][e]      = make_float2(v.x, v.z);
        *(float2*)&s_img2[r][14 + e] = make_float2(v.y, v.w);
    }
    for (int i = tid; i < 72; i += 256) (&s_w1[0][0])[i] = w1g[i];
    for (int i = tid; i < 1152; i += 256) {            // s_w2n[((k*2+g)*16+c)*4+l] = w2[c][g*4+l][k]
        int l = i & 3, c = (i >> 2) & 15, g = (i >> 6) & 1, k = i >> 7;
        s_w2n[i] = w2g[(c * 8 + g * 4 + l) * 9 + k];
    }
    for (int i = tid; i < 4608; i += 256) {            // s_w3n[((k*4+g)*32+c)*4+l] = w3[c][g*4+l][k]
        int l = i & 3, c = (i >> 2) & 31, g = (i >> 7) & 3, k = i >> 9;
        s_w3n[i] = w3g[(c * 16 + g * 4 + l) * 9 + k];
    }
    for (int i = tid; i < 320; i += 256) { int j = i >> 5, c2 = i & 31; s_wdt[c2 * 10 + j] = wdg[i]; }
    if (tid < 8)  s_b1[tid] = b1g[tid];
    if (tid < 16) s_b2[tid] = b2g[tid];
    if (tid < 32) s_b3[tid] = b3g[tid];
    if (tid < 10) s_bd[tid] = bdg[tid];
    __syncthreads();

    // ---- stage 1: conv1(1->8)+relu+pool2, only (y,x) in [0,10)^2 needed. 800 items.
    for (int idx = tid; idx < 800; idx += 256) {
        int c   = idx / 100;
        int rem = idx - c * 100;
        int y   = rem / 10;
        int x   = rem - y * 10;
        int r0  = 2 * y;
        float p[4][4];
        #pragma unroll
        for (int i = 0; i < 4; i++) {
            const float* rp = &s_img2[r0 + i][0];
            p[i][0] = rp[x];            // col 2x
            p[i][1] = rp[14 + x];       // col 2x+1
            p[i][2] = rp[x + 1];        // col 2x+2
            p[i][3] = rp[15 + x];       // col 2x+3
        }
        const float* W = s_w1[c];
        const float bias = s_b1[c];
        float acc = 0.f;
        #pragma unroll
        for (int rr = 0; rr < 2; rr++)
            #pragma unroll
            for (int cc = 0; cc < 2; cc++) {
                float v = bias;
                #pragma unroll
                for (int i = 0; i < 3; i++)
                    #pragma unroll
                    for (int j = 0; j < 3; j++)
                        v += p[rr + i][cc + j] * W[i * 3 + j];
                acc += fmaxf(v, 0.f);
            }
        int slot = (x >> 1) + 5 * (x & 1);
        s_p1n[y][slot][c] = 0.25f * acc;
    }
    __syncthreads();

    // ---- stage 2: conv2(8->16)+relu+pool2, only (y,x) in [0,4)^2 needed. 256 items = 1/thread.
    {
        const int c = tid >> 4;
        const int y = (tid >> 2) & 3;
        const int x = tid & 3;
        const int r0 = 2 * y;
        int slotm[4] = { x, 5 + x, x + 1, 6 + x };     // cols 2x+0..3 -> parity slots
        const float bias = s_b2[c];
        float v00 = bias, v01 = bias, v10 = bias, v11 = bias;
        #pragma unroll
        for (int g = 0; g < 2; g++) {
            float4 wk[9];
            #pragma unroll
            for (int k = 0; k < 9; k++)
                wk[k] = *(const float4*)&s_w2n[((k * 2 + g) * 16 + c) * 4];
            #pragma unroll
            for (int i = 0; i < 4; i++) {
                #pragma unroll
                for (int dx = 0; dx < 4; dx++) {
                    float4 a = *(const float4*)&s_p1n[r0 + i][slotm[dx]][g * 4];
                    #pragma unroll
                    for (int rr = 0; rr < 2; rr++) {
                        int di = i - rr;
                        if (di < 0 || di > 2) continue;
                        #pragma unroll
                        for (int cc = 0; cc < 2; cc++) {
                            int dj = dx - cc;
                            if (dj < 0 || dj > 2) continue;
                            float4 w = wk[di * 3 + dj];
                            float dot = a.x * w.x + a.y * w.y + a.z * w.z + a.w * w.w;
                            if (rr == 0) { if (cc == 0) v00 += dot; else v01 += dot; }
                            else         { if (cc == 0) v10 += dot; else v11 += dot; }
                        }
                    }
                }
            }
        }
        s_p2n[(y * 4 + x) * 16 + c] = 0.25f * (fmaxf(v00, 0.f) + fmaxf(v01, 0.f) +
                                               fmaxf(v10, 0.f) + fmaxf(v11, 0.f));
    }
    __syncthreads();

    // ---- stage 3: conv3(16->32)+relu at the 2x2 window. thread=(c,u,v), 128 threads.
    if (tid < 128) {
        const int c = tid >> 2;
        const int u = (tid >> 1) & 1;
        const int v = tid & 1;
        float acc = s_b3[c];
        #pragma unroll
        for (int g = 0; g < 4; g++) {
            #pragma unroll
            for (int i = 0; i < 3; i++)
                #pragma unroll
                for (int j = 0; j < 3; j++) {
                    int k = i * 3 + j;
                    float4 a = *(const float4*)&s_p2n[((u + i) * 4 + (v + j)) * 16 + g * 4];
                    float4 w = *(const float4*)&s_w3n[((k * 4 + g) * 32 + c) * 4];
                    acc += a.x * w.x + a.y * w.y + a.z * w.z + a.w * w.w;
                }
        }
        s_c3[c][(u << 1) | v] = fmaxf(acc, 0.f);
    }
    __syncthreads();
    if (tid < 32)
        s_p3[tid] = 0.25f * (s_c3[tid][0] + s_c3[tid][1] + s_c3[tid][2] + s_c3[tid][3]);
    __syncthreads();

    // ---- dense + softmax + guards
    if (tid < 10) {
        float acc = s_bd[tid];
        #pragma unroll
        for (int c2 = 0; c2 < 32; c2++) acc += s_p3[c2] * s_wdt[c2 * 10 + tid];
        s_logit[tid] = acc;
    }
    __syncthreads();
    if (tid < 10) {
        float mx = s_logit[0];
        #pragma unroll
        for (int k = 1; k < 10; k++) mx = fmaxf(mx, s_logit[k]);
        float ssum = 0.f;
        #pragma unroll
        for (int k = 0; k < 10; k++) ssum += __expf(s_logit[k] - mx);
        float p = __expf(s_logit[tid] - mx) / ssum;
        s_prob[tid] = p;
        out[(size_t)m * 10 + tid] = p;                 // all_cnn_preds (N,B,10)
    }
    __syncthreads();
    if (tid < 6) {
        // rules: [p8, p4+p6, p0+p2, p7+p9, p5, p1+p3]
        int ia = (0x157048 >> (tid * 4)) & 0xF;
        int ib = (0x3F926F >> (tid * 4)) & 0xF;
        float gv = s_prob[ia] + (ib < 10 ? s_prob[ib] : 0.f);
        out[81920 + (size_t)m * 6 + tid] = gv;         // all_guard_preds (N,B,6)
        g_ws[(size_t)m * 6 + tid] = gv;                // scratch for recurrence
    }
}

// 11 blocks x 256 threads. lane = bb*10 + j inside a wave (6 batches/wave).
// M column in 54 registers; state exchange via __shfl — zero barriers in the loop.
__global__ __launch_bounds__(256) void sfa_kernel(
    const float* __restrict__ trans,
    const float* __restrict__ g_ws,
    float* __restrict__ out)
{
    __shared__ float M[600];           // [r][i][j]
    const int tid  = threadIdx.x;
    const int lane = tid & 63;
    const int wv   = tid >> 6;

    if (tid < 54) {
        int r = tid / 9, i = tid - r * 9;
        const float* row = trans + (size_t)(r * 9 + i) * 10;
        float x[10], mx = -1e30f;
        #pragma unroll
        for (int j = 0; j < 10; j++) { x[j] = 10.f * row[j]; mx = fmaxf(mx, x[j]); }
        float s = 0.f;
        #pragma unroll
        for (int j = 0; j < 10; j++) { x[j] = __expf(x[j] - mx); s += x[j]; }
        float inv = 1.f / s;
        #pragma unroll
        for (int j = 0; j < 10; j++) M[(r * 9 + i) * 10 + j] = x[j] * inv;
    }
    __syncthreads();

    const int bb    = lane / 10;                    // batch-in-wave, 0..6 (6 invalid)
    const int j     = lane - bb * 10;
    const int base  = bb * 10;
    const bool ok   = (bb < 6);
    int batch = blockIdx.x * 24 + wv * 6 + bb;
    const bool live = ok && (batch < 256);
    if (!live) batch = 0;

    float Mreg[54];
    #pragma unroll
    for (int k = 0; k < 54; k++) Mreg[k] = M[k * 10 + j];

    float stj = (j == 0) ? 1.f : 0.f;

    for (int nn = 0; nn < 32; nn++) {
        const float* gp = g_ws + ((size_t)nn * 256 + batch) * 6;
        float2 ga = *(const float2*)(gp);
        float2 gb = *(const float2*)(gp + 2);
        float2 gc = *(const float2*)(gp + 4);
        float g[6] = {ga.x, ga.y, gb.x, gb.y, gc.x, gc.y};

        float st[10];
        #pragma unroll
        for (int i = 0; i < 10; i++) st[i] = __shfl(stj, base + i, 64);

        float gsum = g[0] + g[1] + g[2] + g[3] + g[4] + g[5];
        float ns = (j == 9) ? gsum * st[9] : 0.f;   // accepting row
        #pragma unroll
        for (int r = 0; r < 6; r++) {
            float h = 0.f;
            #pragma unroll
            for (int i = 0; i < 9; i++) h += st[i] * Mreg[r * 9 + i];
            ns += g[r] * h;
        }
        stj = ns;
    }
    if (live) out[131072 + (size_t)batch * 10 + j] = stj;   // state_final (B,10)
}

extern "C" void kernel_launch(void* const* d_in, const int* in_sizes, int n_in,
                              void* d_out, int out_size, void* d_ws, size_t ws_size,
                              hipStream_t stream) {
    const float* seq = (const float*)d_in[0];
    const float* w1  = (const float*)d_in[1];
    const float* b1  = (const float*)d_in[2];
    const float* w2  = (const float*)d_in[3];
    const float* b2  = (const float*)d_in[4];
    const float* w3  = (const float*)d_in[5];
    const float* b3  = (const float*)d_in[6];
    const float* wd  = (const float*)d_in[7];
    const float* bd  = (const float*)d_in[8];
    const float* tr  = (const float*)d_in[9];
    float* out  = (float*)d_out;
    float* g_ws = (float*)d_ws;   // 8192*6 fp32 guard scratch

    cnn_kernel<<<8192, 256, 0, stream>>>(seq, w1, b1, w2, b2, w3, b3, wd, bd, out, g_ws);
    sfa_kernel<<<11, 256, 0, stream>>>(tr, g_ws, out);
}

// Round 7
// 177.619 us; speedup vs baseline: 2.3845x; 1.0767x over previous
//
#include <hip/hip_runtime.h>

// ---- prep: transpose weights into g_ws once (1 block). Layouts match cnn reads.
__global__ __launch_bounds__(256) void prep_kernel(
    const float* __restrict__ w2g, const float* __restrict__ w3g,
    const float* __restrict__ wdg, float* __restrict__ wsW)
{
    const int tid = threadIdx.x;
    for (int i = tid; i < 1152; i += 256) {            // w2n[((k*2+g)*16+c)*4+l] = w2[c][g*4+l][k]
        int l = i & 3, c = (i >> 2) & 15, g = (i >> 6) & 1, k = i >> 7;
        wsW[i] = w2g[(c * 8 + g * 4 + l) * 9 + k];
    }
    for (int i = tid; i < 4608; i += 256) {            // w3n[((k*4+g)*32+c)*4+l] = w3[c][g*4+l][k]
        int l = i & 3, c = (i >> 2) & 31, g = (i >> 7) & 3, k = i >> 9;
        wsW[1152 + i] = w3g[(c * 16 + g * 4 + l) * 9 + k];
    }
    for (int i = tid; i < 320; i += 256) {             // wdt[c2*10+j] = wd[j][c2]
        int j = i >> 5, c2 = i & 31;
        wsW[5760 + c2 * 10 + j] = wdg[i];
    }
}

// One block per image (8192 = N*B images), 256 threads. All fp32.
// Activations in LDS (parity de-interleaved / ic-fastest); ALL weights read from
// global (prep-transposed, L1-resident) — LDS pipe reserved for activations.
__global__ __launch_bounds__(256) void cnn_kernel(
    const float* __restrict__ seq,
    const float* __restrict__ w1g, const float* __restrict__ b1g,
    const float* __restrict__ b2g, const float* __restrict__ b3g,
    const float* __restrict__ bdg, const float* __restrict__ wsW,
    float* __restrict__ out, float* __restrict__ g_ws)
{
    __shared__ __align__(16) float s_img2[28][28];   // row: [0..13]=even cols, [14..27]=odd cols
    __shared__ __align__(16) float s_p1n[10][11][8]; // [y][col-slot][ic], slot=(c'>>1)+5*(c'&1)
    __shared__ __align__(16) float s_p2n[256];       // [pixel(y*4+x)][16 ic]
    __shared__ float s_c3[32][4];
    __shared__ float s_p3[32];
    __shared__ float s_logit[10];
    __shared__ float s_prob[10];

    const int tid = threadIdx.x;
    const int m   = blockIdx.x;        // image id = n*256 + b, n = t*4 + d
    const int n   = m >> 8;
    const int b   = m & 255;
    const int t   = n >> 2;
    const int d   = n & 3;

    // ---- stage image (parity de-interleave)
    const float4* src4 = (const float4*)(seq + (((size_t)b * 8 + t) * 4 + d) * 784);
    if (tid < 196) {
        float4 v = src4[tid];
        int flat = tid * 4;
        int r  = flat / 28;
        int cb = flat - r * 28;        // multiple of 4
        int e  = cb >> 1;
        *(float2*)&s_img2[r][e]      = make_float2(v.x, v.z);
        *(float2*)&s_img2[r][14 + e] = make_float2(v.y, v.w);
    }
    __syncthreads();

    // ---- stage 1: conv1(1->8)+relu+pool2 at the 100 needed positions.
    // thread=(y,x); 4x4 patch in registers once; w1/b1 uniform (scalar loads).
    if (tid < 100) {
        const int y = tid / 10;
        const int x = tid - y * 10;
        const int r0 = 2 * y;
        float p[4][4];
        #pragma unroll
        for (int i = 0; i < 4; i++) {
            const float* rp = &s_img2[r0 + i][0];
            p[i][0] = rp[x];            // col 2x
            p[i][1] = rp[14 + x];       // col 2x+1
            p[i][2] = rp[x + 1];        // col 2x+2
            p[i][3] = rp[15 + x];       // col 2x+3
        }
        float res[8];
        #pragma unroll
        for (int c = 0; c < 8; c++) {
            float w[9];
            #pragma unroll
            for (int k = 0; k < 9; k++) w[k] = w1g[c * 9 + k];   // uniform -> s_load
            const float bias = b1g[c];
            float acc = 0.f;
            #pragma unroll
            for (int rr = 0; rr < 2; rr++)
                #pragma unroll
                for (int cc = 0; cc < 2; cc++) {
                    float v = bias;
                    #pragma unroll
                    for (int i = 0; i < 3; i++)
                        #pragma unroll
                        for (int j = 0; j < 3; j++)
                            v += p[rr + i][cc + j] * w[i * 3 + j];
                    acc += fmaxf(v, 0.f);
                }
            res[c] = 0.25f * acc;
        }
        const int slot = (x >> 1) + 5 * (x & 1);
        *(float4*)&s_p1n[y][slot][0] = make_float4(res[0], res[1], res[2], res[3]);
        *(float4*)&s_p1n[y][slot][4] = make_float4(res[4], res[5], res[6], res[7]);
    }
    __syncthreads();

    // ---- stage 2: conv2(8->16)+relu+pool2 at (y,x) in [0,4)^2. 256 items = 1/thread.
    {
        const int c = tid >> 4;
        const int y = (tid >> 2) & 3;
        const int x = tid & 3;
        const int r0 = 2 * y;
        int slotm[4] = { x, 5 + x, x + 1, 6 + x };     // cols 2x+0..3 -> parity slots
        const float bias = b2g[c];
        float v00 = bias, v01 = bias, v10 = bias, v11 = bias;
        #pragma unroll
        for (int g = 0; g < 2; g++) {
            float4 wk[9];
            #pragma unroll
            for (int k = 0; k < 9; k++)
                wk[k] = *(const float4*)&wsW[((k * 2 + g) * 16 + c) * 4];   // L1
            #pragma unroll
            for (int i = 0; i < 4; i++) {
                #pragma unroll
                for (int dx = 0; dx < 4; dx++) {
                    float4 a = *(const float4*)&s_p1n[r0 + i][slotm[dx]][g * 4];
                    #pragma unroll
                    for (int rr = 0; rr < 2; rr++) {
                        int di = i - rr;
                        if (di < 0 || di > 2) continue;
                        #pragma unroll
                        for (int cc = 0; cc < 2; cc++) {
                            int dj = dx - cc;
                            if (dj < 0 || dj > 2) continue;
                            float4 w = wk[di * 3 + dj];
                            float dot = a.x * w.x + a.y * w.y + a.z * w.z + a.w * w.w;
                            if (rr == 0) { if (cc == 0) v00 += dot; else v01 += dot; }
                            else         { if (cc == 0) v10 += dot; else v11 += dot; }
                        }
                    }
                }
            }
        }
        s_p2n[(y * 4 + x) * 16 + c] = 0.25f * (fmaxf(v00, 0.f) + fmaxf(v01, 0.f) +
                                               fmaxf(v10, 0.f) + fmaxf(v11, 0.f));
    }
    __syncthreads();

    // ---- stage 3: conv3(16->32)+relu at the 2x2 window. thread=(c,u,v), 128 threads.
    if (tid < 128) {
        const int c = tid >> 2;
        const int u = (tid >> 1) & 1;
        const int v = tid & 1;
        const float* w3n = wsW + 1152;
        float acc = b3g[c];
        #pragma unroll
        for (int g = 0; g < 4; g++) {
            #pragma unroll
            for (int i = 0; i < 3; i++)
                #pragma unroll
                for (int j = 0; j < 3; j++) {
                    int k = i * 3 + j;
                    float4 a = *(const float4*)&s_p2n[((u + i) * 4 + (v + j)) * 16 + g * 4];
                    float4 w = *(const float4*)&w3n[((k * 4 + g) * 32 + c) * 4];   // L1
                    acc += a.x * w.x + a.y * w.y + a.z * w.z + a.w * w.w;
                }
        }
        s_c3[c][(u << 1) | v] = fmaxf(acc, 0.f);
    }
    __syncthreads();
    if (tid < 32)
        s_p3[tid] = 0.25f * (s_c3[tid][0] + s_c3[tid][1] + s_c3[tid][2] + s_c3[tid][3]);
    __syncthreads();

    // ---- dense + softmax + guards
    if (tid < 10) {
        const float* wdt = wsW + 5760;
        float acc = bdg[tid];
        #pragma unroll
        for (int c2 = 0; c2 < 32; c2++) acc += s_p3[c2] * wdt[c2 * 10 + tid];
        s_logit[tid] = acc;
    }
    __syncthreads();
    if (tid < 10) {
        float mx = s_logit[0];
        #pragma unroll
        for (int k = 1; k < 10; k++) mx = fmaxf(mx, s_logit[k]);
        float ssum = 0.f;
        #pragma unroll
        for (int k = 0; k < 10; k++) ssum += __expf(s_logit[k] - mx);
        float p = __expf(s_logit[tid] - mx) / ssum;
        s_prob[tid] = p;
        out[(size_t)m * 10 + tid] = p;                 // all_cnn_preds (N,B,10)
    }
    __syncthreads();
    if (tid < 6) {
        // rules: [p8, p4+p6, p0+p2, p7+p9, p5, p1+p3]
        int ia = (0x157048 >> (tid * 4)) & 0xF;
        int ib = (0x3F926F >> (tid * 4)) & 0xF;
        float gv = s_prob[ia] + (ib < 10 ? s_prob[ib] : 0.f);
        out[81920 + (size_t)m * 6 + tid] = gv;         // all_guard_preds (N,B,6)
        g_ws[(size_t)m * 6 + tid] = gv;                // scratch for recurrence
    }
}

// 11 blocks x 256 threads. lane = bb*10 + j inside a wave (6 batches/wave).
// M column in 54 registers; state exchange via __shfl — zero barriers in the loop.
__global__ __launch_bounds__(256) void sfa_kernel(
    const float* __restrict__ trans,
    const float* __restrict__ g_ws,
    float* __restrict__ out)
{
    __shared__ float M[600];           // [r][i][j]
    const int tid  = threadIdx.x;
    const int lane = tid & 63;
    const int wv   = tid >> 6;

    if (tid < 54) {
        int r = tid / 9, i = tid - r * 9;
        const float* row = trans + (size_t)(r * 9 + i) * 10;
        float x[10], mx = -1e30f;
        #pragma unroll
        for (int j = 0; j < 10; j++) { x[j] = 10.f * row[j]; mx = fmaxf(mx, x[j]); }
        float s = 0.f;
        #pragma unroll
        for (int j = 0; j < 10; j++) { x[j] = __expf(x[j] - mx); s += x[j]; }
        float inv = 1.f / s;
        #pragma unroll
        for (int j = 0; j < 10; j++) M[(r * 9 + i) * 10 + j] = x[j] * inv;
    }
    __syncthreads();

    const int bb    = lane / 10;                    // batch-in-wave, 0..6 (6 invalid)
    const int j     = lane - bb * 10;
    const int base  = bb * 10;
    const bool ok   = (bb < 6);
    int batch = blockIdx.x * 24 + wv * 6 + bb;
    const bool live = ok && (batch < 256);
    if (!live) batch = 0;

    float Mreg[54];
    #pragma unroll
    for (int k = 0; k < 54; k++) Mreg[k] = M[k * 10 + j];

    float stj = (j == 0) ? 1.f : 0.f;

    for (int nn = 0; nn < 32; nn++) {
        const float* gp = g_ws + ((size_t)nn * 256 + batch) * 6;
        float2 ga = *(const float2*)(gp);
        float2 gb = *(const float2*)(gp + 2);
        float2 gc = *(const float2*)(gp + 4);
        float g[6] = {ga.x, ga.y, gb.x, gb.y, gc.x, gc.y};

        float st[10];
        #pragma unroll
        for (int i = 0; i < 10; i++) st[i] = __shfl(stj, base + i, 64);

        float gsum = g[0] + g[1] + g[2] + g[3] + g[4] + g[5];
        float ns = (j == 9) ? gsum * st[9] : 0.f;   // accepting row
        #pragma unroll
        for (int r = 0; r < 6; r++) {
            float h = 0.f;
            #pragma unroll
            for (int i = 0; i < 9; i++) h += st[i] * Mreg[r * 9 + i];
            ns += g[r] * h;
        }
        stj = ns;
    }
    if (live) out[131072 + (size_t)batch * 10 + j] = stj;   // state_final (B,10)
}

extern "C" void kernel_launch(void* const* d_in, const int* in_sizes, int n_in,
                              void* d_out, int out_size, void* d_ws, size_t ws_size,
                              hipStream_t stream) {
    const float* seq = (const float*)d_in[0];
    const float* w1  = (const float*)d_in[1];
    const float* b1  = (const float*)d_in[2];
    const float* w2  = (const float*)d_in[3];
    const float* b2  = (const float*)d_in[4];
    const float* w3  = (const float*)d_in[5];
    const float* b3  = (const float*)d_in[6];
    const float* wd  = (const float*)d_in[7];
    const float* bd  = (const float*)d_in[8];
    const float* tr  = (const float*)d_in[9];
    float* out  = (float*)d_out;
    float* g_ws = (float*)d_ws;            // [0, 49152): guard probs scratch
    float* wsW  = g_ws + 49152;            // [49152, 49152+6080): prepped weights (~24 KB)

    prep_kernel<<<1, 256, 0, stream>>>(w2, w3, wd, wsW);
    cnn_kernel<<<8192, 256, 0, stream>>>(seq, w1, b1, b2, b3, bd, wsW, out, g_ws);
    sfa_kernel<<<11, 256, 0, stream>>>(tr, g_ws, out);
}

// Round 8
// 156.222 us; speedup vs baseline: 2.7111x; 1.1370x over previous
//
#include <hip/hip_runtime.h>

// ---- prep: transpose weights into g_ws once (1 block). Layouts match cnn reads.
__global__ __launch_bounds__(256) void prep_kernel(
    const float* __restrict__ w2g, const float* __restrict__ w3g,
    const float* __restrict__ wdg, float* __restrict__ wsW)
{
    const int tid = threadIdx.x;
    for (int i = tid; i < 1152; i += 256) {            // w2n[((k*2+g)*16+c)*4+l] = w2[c][g*4+l][k]
        int l = i & 3, c = (i >> 2) & 15, g = (i >> 6) & 1, k = i >> 7;
        wsW[i] = w2g[(c * 8 + g * 4 + l) * 9 + k];
    }
    for (int i = tid; i < 4608; i += 256) {            // w3n[((k*4+g)*32+c)*4+l] = w3[c][g*4+l][k]
        int l = i & 3, c = (i >> 2) & 31, g = (i >> 7) & 3, k = i >> 9;
        wsW[1152 + i] = w3g[(c * 16 + g * 4 + l) * 9 + k];
    }
    for (int i = tid; i < 320; i += 256) {             // wdt[c2*10+j] = wd[j][c2]
        int j = i >> 5, c2 = i & 31;
        wsW[5760 + c2 * 10 + j] = wdg[i];
    }
}

// 4 images per block (grid 2048), 256 threads; wave w handles image w in stages 2/3.
// Stage2: thread=(img,pos,oc-quad) -> act reads amortized over 4 oc.
__global__ __launch_bounds__(256) void cnn_kernel(
    const float* __restrict__ seq,
    const float* __restrict__ w1g, const float* __restrict__ b1g,
    const float* __restrict__ b2g, const float* __restrict__ b3g,
    const float* __restrict__ bdg, const float* __restrict__ wsW,
    float* __restrict__ out, float* __restrict__ g_ws)
{
    __shared__ __align__(16) float s_img2[4][28][28];     // parity rows: [0..13]=even cols, [14..27]=odd
    __shared__ __align__(16) float s_p1n[4][2][10][11][4];// [img][g][y][slot][l] ; ic = g*4+l
    __shared__ __align__(16) float s_p2n[4][16][16];      // [img][pixel(y*4+x)][16 ic]
    __shared__ float s_c3[4][32][4];
    __shared__ float s_p3[4][32];
    __shared__ float s_logit[4][10];
    __shared__ float s_prob[4][10];

    const int tid   = threadIdx.x;
    const int mbase = blockIdx.x * 4;

    // ---- stage images (parity de-interleave); thread loads one float4 per image
    if (tid < 196) {
        #pragma unroll
        for (int img = 0; img < 4; img++) {
            const int m = mbase + img;
            const int b = m & 255, nn = m >> 8;
            const int t = nn >> 2, dd = nn & 3;
            const float4* s4 = (const float4*)(seq + (((size_t)b * 8 + t) * 4 + dd) * 784);
            float4 v = s4[tid];
            int flat = tid * 4;
            int r  = flat / 28;
            int cb = flat - r * 28;       // multiple of 4
            int e  = cb >> 1;
            *(float2*)&s_img2[img][r][e]      = make_float2(v.x, v.z);
            *(float2*)&s_img2[img][r][14 + e] = make_float2(v.y, v.w);
        }
    }
    __syncthreads();

    // ---- stage 1: conv1(1->8)+relu+pool2 at the 100 needed positions per image (400 items).
    for (int idx = tid; idx < 400; idx += 256) {
        const int img = idx / 100;
        const int rem = idx - img * 100;
        const int y   = rem / 10;
        const int x   = rem - y * 10;
        const int r0  = 2 * y;
        float p[4][4];
        #pragma unroll
        for (int i = 0; i < 4; i++) {
            const float* rp = &s_img2[img][r0 + i][0];
            p[i][0] = rp[x];            // col 2x
            p[i][1] = rp[14 + x];       // col 2x+1
            p[i][2] = rp[x + 1];        // col 2x+2
            p[i][3] = rp[15 + x];       // col 2x+3
        }
        float res[8];
        #pragma unroll
        for (int c = 0; c < 8; c++) {
            float w[9];
            #pragma unroll
            for (int k = 0; k < 9; k++) w[k] = w1g[c * 9 + k];   // uniform -> s_load
            const float bias = b1g[c];
            float acc = 0.f;
            #pragma unroll
            for (int rr = 0; rr < 2; rr++)
                #pragma unroll
                for (int cc = 0; cc < 2; cc++) {
                    float v = bias;
                    #pragma unroll
                    for (int i = 0; i < 3; i++)
                        #pragma unroll
                        for (int j = 0; j < 3; j++)
                            v += p[rr + i][cc + j] * w[i * 3 + j];
                    acc += fmaxf(v, 0.f);
                }
            res[c] = 0.25f * acc;
        }
        const int slot = (x >> 1) + 5 * (x & 1);
        *(float4*)&s_p1n[img][0][y][slot][0] = make_float4(res[0], res[1], res[2], res[3]);
        *(float4*)&s_p1n[img][1][y][slot][0] = make_float4(res[4], res[5], res[6], res[7]);
    }
    __syncthreads();

    const int img2 = tid >> 6;          // wave = image
    const int t6   = tid & 63;

    // ---- stage 2: conv2(8->16)+relu+pool2; thread=(img, pos, oc-quad). 1152 FMA/thread.
    {
        const int pos = t6 >> 2;        // 0..15 pooled position
        const int q   = t6 & 3;         // oc quad: channels q*4..q*4+3
        const int y   = pos >> 2, x = pos & 3;
        const int r0  = 2 * y;
        const int slotm[4] = { x, 5 + x, x + 1, 6 + x };
        float v[4][4];                  // [oc][rr*2+cc]
        #pragma unroll
        for (int oc = 0; oc < 4; oc++) {
            const float bias = b2g[q * 4 + oc];
            #pragma unroll
            for (int w2 = 0; w2 < 4; w2++) v[oc][w2] = bias;
        }
        #pragma unroll
        for (int g = 0; g < 2; g++) {
            float4 a[4][4];
            #pragma unroll
            for (int i = 0; i < 4; i++)
                #pragma unroll
                for (int dx = 0; dx < 4; dx++)
                    a[i][dx] = *(const float4*)&s_p1n[img2][g][r0 + i][slotm[dx]][0];
            #pragma unroll
            for (int k = 0; k < 9; k++) {
                const int di = k / 3, dj = k - di * 3;
                #pragma unroll
                for (int oc = 0; oc < 4; oc++) {
                    float4 wk = *(const float4*)&wsW[((k * 2 + g) * 16 + q * 4 + oc) * 4];
                    #pragma unroll
                    for (int rr = 0; rr < 2; rr++)
                        #pragma unroll
                        for (int cc = 0; cc < 2; cc++) {
                            float4 aa = a[rr + di][cc + dj];
                            v[oc][rr * 2 + cc] += aa.x * wk.x + aa.y * wk.y +
                                                  aa.z * wk.z + aa.w * wk.w;
                        }
                }
            }
        }
        float res[4];
        #pragma unroll
        for (int oc = 0; oc < 4; oc++)
            res[oc] = 0.25f * (fmaxf(v[oc][0], 0.f) + fmaxf(v[oc][1], 0.f) +
                               fmaxf(v[oc][2], 0.f) + fmaxf(v[oc][3], 0.f));
        *(float4*)&s_p2n[img2][pos][q * 4] = make_float4(res[0], res[1], res[2], res[3]);
    }
    __syncthreads();

    // ---- stage 3: conv3(16->32)+relu; thread=(img, c, u) computes windows v=0,1.
    {
        const int c = t6 >> 1;
        const int u = t6 & 1;
        const float* w3n = wsW + 1152;
        float acc0 = b3g[c], acc1 = acc0;
        #pragma unroll
        for (int g = 0; g < 4; g++) {
            float4 A[3][4];
            #pragma unroll
            for (int i = 0; i < 3; i++)
                #pragma unroll
                for (int jj = 0; jj < 4; jj++)
                    A[i][jj] = *(const float4*)&s_p2n[img2][(u + i) * 4 + jj][g * 4];
            #pragma unroll
            for (int i = 0; i < 3; i++)
                #pragma unroll
                for (int j = 0; j < 3; j++) {
                    const int k = i * 3 + j;
                    float4 wk = *(const float4*)&w3n[((k * 4 + g) * 32 + c) * 4];
                    float4 a0 = A[i][j], a1 = A[i][j + 1];
                    acc0 += a0.x * wk.x + a0.y * wk.y + a0.z * wk.z + a0.w * wk.w;
                    acc1 += a1.x * wk.x + a1.y * wk.y + a1.z * wk.z + a1.w * wk.w;
                }
        }
        s_c3[img2][c][u * 2 + 0] = fmaxf(acc0, 0.f);
        s_c3[img2][c][u * 2 + 1] = fmaxf(acc1, 0.f);
    }
    __syncthreads();
    if (t6 < 32)
        s_p3[img2][t6] = 0.25f * (s_c3[img2][t6][0] + s_c3[img2][t6][1] +
                                  s_c3[img2][t6][2] + s_c3[img2][t6][3]);
    __syncthreads();

    // ---- dense + softmax + guards (per wave = per image)
    if (t6 < 10) {
        const float* wdt = wsW + 5760;
        float acc = bdg[t6];
        #pragma unroll
        for (int c2 = 0; c2 < 32; c2++) acc += s_p3[img2][c2] * wdt[c2 * 10 + t6];
        s_logit[img2][t6] = acc;
    }
    __syncthreads();
    if (t6 < 10) {
        const int m = mbase + img2;
        float mx = s_logit[img2][0];
        #pragma unroll
        for (int k = 1; k < 10; k++) mx = fmaxf(mx, s_logit[img2][k]);
        float ssum = 0.f;
        #pragma unroll
        for (int k = 0; k < 10; k++) ssum += __expf(s_logit[img2][k] - mx);
        float p = __expf(s_logit[img2][t6] - mx) / ssum;
        s_prob[img2][t6] = p;
        out[(size_t)m * 10 + t6] = p;                  // all_cnn_preds (N,B,10)
    }
    __syncthreads();
    if (t6 < 6) {
        const int m = mbase + img2;
        // rules: [p8, p4+p6, p0+p2, p7+p9, p5, p1+p3]
        int ia = (0x157048 >> (t6 * 4)) & 0xF;
        int ib = (0x3F926F >> (t6 * 4)) & 0xF;
        float gv = s_prob[img2][ia] + (ib < 10 ? s_prob[img2][ib] : 0.f);
        out[81920 + (size_t)m * 6 + t6] = gv;          // all_guard_preds (N,B,6)
        g_ws[(size_t)m * 6 + t6] = gv;                 // scratch for recurrence
    }
}

// 11 blocks x 256 threads. lane = bb*10 + j inside a wave (6 batches/wave).
// M column in 54 registers; state exchange via __shfl — zero barriers in the loop.
__global__ __launch_bounds__(256) void sfa_kernel(
    const float* __restrict__ trans,
    const float* __restrict__ g_ws,
    float* __restrict__ out)
{
    __shared__ float M[600];           // [r][i][j]
    const int tid  = threadIdx.x;
    const int lane = tid & 63;
    const int wv   = tid >> 6;

    if (tid < 54) {
        int r = tid / 9, i = tid - r * 9;
        const float* row = trans + (size_t)(r * 9 + i) * 10;
        float x[10], mx = -1e30f;
        #pragma unroll
        for (int j = 0; j < 10; j++) { x[j] = 10.f * row[j]; mx = fmaxf(mx, x[j]); }
        float s = 0.f;
        #pragma unroll
        for (int j = 0; j < 10; j++) { x[j] = __expf(x[j] - mx); s += x[j]; }
        float inv = 1.f / s;
        #pragma unroll
        for (int j = 0; j < 10; j++) M[(r * 9 + i) * 10 + j] = x[j] * inv;
    }
    __syncthreads();

    const int bb    = lane / 10;                    // batch-in-wave, 0..6 (6 invalid)
    const int j     = lane - bb * 10;
    const int base  = bb * 10;
    const bool ok   = (bb < 6);
    int batch = blockIdx.x * 24 + wv * 6 + bb;
    const bool live = ok && (batch < 256);
    if (!live) batch = 0;

    float Mreg[54];
    #pragma unroll
    for (int k = 0; k < 54; k++) Mreg[k] = M[k * 10 + j];

    float stj = (j == 0) ? 1.f : 0.f;

    for (int nn = 0; nn < 32; nn++) {
        const float* gp = g_ws + ((size_t)nn * 256 + batch) * 6;
        float2 ga = *(const float2*)(gp);
        float2 gb = *(const float2*)(gp + 2);
        float2 gc = *(const float2*)(gp + 4);
        float g[6] = {ga.x, ga.y, gb.x, gb.y, gc.x, gc.y};

        float st[10];
        #pragma unroll
        for (int i = 0; i < 10; i++) st[i] = __shfl(stj, base + i, 64);

        float gsum = g[0] + g[1] + g[2] + g[3] + g[4] + g[5];
        float ns = (j == 9) ? gsum * st[9] : 0.f;   // accepting row
        #pragma unroll
        for (int r = 0; r < 6; r++) {
            float h = 0.f;
            #pragma unroll
            for (int i = 0; i < 9; i++) h += st[i] * Mreg[r * 9 + i];
            ns += g[r] * h;
        }
        stj = ns;
    }
    if (live) out[131072 + (size_t)batch * 10 + j] = stj;   // state_final (B,10)
}

extern "C" void kernel_launch(void* const* d_in, const int* in_sizes, int n_in,
                              void* d_out, int out_size, void* d_ws, size_t ws_size,
                              hipStream_t stream) {
    const float* seq = (const float*)d_in[0];
    const float* w1  = (const float*)d_in[1];
    const float* b1  = (const float*)d_in[2];
    const float* w2  = (const float*)d_in[3];
    const float* b2  = (const float*)d_in[4];
    const float* w3  = (const float*)d_in[5];
    const float* b3  = (const float*)d_in[6];
    const float* wd  = (const float*)d_in[7];
    const float* bd  = (const float*)d_in[8];
    const float* tr  = (const float*)d_in[9];
    float* out  = (float*)d_out;
    float* g_ws = (float*)d_ws;            // [0, 49152): guard probs scratch
    float* wsW  = g_ws + 49152;            // prepped weights (~24 KB)

    prep_kernel<<<1, 256, 0, stream>>>(w2, w3, wd, wsW);
    cnn_kernel<<<2048, 256, 0, stream>>>(seq, w1, b1, b2, b3, bd, wsW, out, g_ws);
    sfa_kernel<<<11, 256, 0, stream>>>(tr, g_ws, out);
}

// Round 9
// 148.747 us; speedup vs baseline: 2.8473x; 1.0503x over previous
//
#include <hip/hip_runtime.h>

typedef _Float16 half_t;
typedef _Float16 h2 __attribute__((ext_vector_type(2)));
typedef _Float16 h4 __attribute__((ext_vector_type(4)));

__device__ __forceinline__ float fdot2f(h2 a, h2 b, float c) {
#if __has_builtin(__builtin_amdgcn_fdot2)
    return __builtin_amdgcn_fdot2(a, b, c, false);
#else
    return c + (float)a.x * (float)b.x + (float)a.y * (float)b.y;
#endif
}

// ---- prep: weights -> ws once. Layout: wdt fp32 [0,320) ; w2h half [320*4 ..) ; w3h after.
__global__ __launch_bounds__(256) void prep_kernel(
    const float* __restrict__ w2g, const float* __restrict__ w3g,
    const float* __restrict__ wdg, float* __restrict__ wsW)
{
    const int tid = threadIdx.x;
    half_t* w2h = (half_t*)(wsW + 320);
    half_t* w3h = w2h + 1152;
    for (int i = tid; i < 320; i += 256) {             // wdt[c2*10+j] = wd[j][c2]
        int j = i >> 5, c2 = i & 31;
        wsW[c2 * 10 + j] = wdg[i];
    }
    for (int i = tid; i < 1152; i += 256) {            // w2h[((k*2+g)*16+c)*4+l] = w2[c][g*4+l][k]
        int l = i & 3, c = (i >> 2) & 15, g = (i >> 6) & 1, k = i >> 7;
        w2h[i] = (half_t)w2g[(c * 8 + g * 4 + l) * 9 + k];
    }
    for (int i = tid; i < 4608; i += 256) {            // w3h[((k*4+g)*32+c)*4+l] = w3[c][g*4+l][k]
        int l = i & 3, c = (i >> 2) & 31, g = (i >> 7) & 3, k = i >> 9;
        w3h[i] = (half_t)w3g[(c * 16 + g * 4 + l) * 9 + k];
    }
}

// 4 images per block (grid 2048), 256 threads; wave = image for stages 2/3.
// Acts in fp16 LDS; stages 2/3 use v_dot2_f32_f16 (fp32 accumulate).
__global__ __launch_bounds__(256) void cnn_kernel(
    const float* __restrict__ seq,
    const float* __restrict__ w1g, const float* __restrict__ b1g,
    const float* __restrict__ b2g, const float* __restrict__ b3g,
    const float* __restrict__ bdg, const float* __restrict__ wsW,
    float* __restrict__ out, float* __restrict__ g_ws)
{
    __shared__ __align__(16) half_t s_img2[4][28][28];      // parity: [0..13]=even cols, [14..27]=odd
    __shared__ __align__(16) half_t s_p1n[4][2][10][11][4]; // [img][g][y][slot][l]; ic=g*4+l
    __shared__ __align__(16) half_t s_p2n[4][16][16];       // [img][pixel(y*4+x)][16 ic]
    __shared__ float s_c3[4][32][4];
    __shared__ float s_p3[4][32];
    __shared__ float s_logit[4][10];
    __shared__ float s_prob[4][10];

    const int tid   = threadIdx.x;
    const int mbase = blockIdx.x * 4;
    const float*  wdt = wsW;
    const half_t* w2h = (const half_t*)(wsW + 320);
    const half_t* w3h = w2h + 1152;

    // ---- stage images (parity de-interleave, fp32 -> fp16)
    if (tid < 196) {
        #pragma unroll
        for (int img = 0; img < 4; img++) {
            const int m = mbase + img;
            const int b = m & 255, nn = m >> 8;
            const int t = nn >> 2, dd = nn & 3;
            const float4* s4 = (const float4*)(seq + (((size_t)b * 8 + t) * 4 + dd) * 784);
            float4 v = s4[tid];
            int flat = tid * 4;
            int r  = flat / 28;
            int cb = flat - r * 28;       // multiple of 4
            int e  = cb >> 1;
            h2 ev = { (half_t)v.x, (half_t)v.z };
            h2 od = { (half_t)v.y, (half_t)v.w };
            *(h2*)&s_img2[img][r][e]      = ev;
            *(h2*)&s_img2[img][r][14 + e] = od;
        }
    }
    __syncthreads();

    // ---- stage 1: conv1(1->8)+relu+pool2 at the 100 needed positions per image (400 items). fp32 math.
    for (int idx = tid; idx < 400; idx += 256) {
        const int img = idx / 100;
        const int rem = idx - img * 100;
        const int y   = rem / 10;
        const int x   = rem - y * 10;
        const int r0  = 2 * y;
        float p[4][4];
        #pragma unroll
        for (int i = 0; i < 4; i++) {
            const half_t* rp = &s_img2[img][r0 + i][0];
            p[i][0] = (float)rp[x];
            p[i][1] = (float)rp[14 + x];
            p[i][2] = (float)rp[x + 1];
            p[i][3] = (float)rp[15 + x];
        }
        float res[8];
        #pragma unroll
        for (int c = 0; c < 8; c++) {
            float w[9];
            #pragma unroll
            for (int k = 0; k < 9; k++) w[k] = w1g[c * 9 + k];   // uniform -> s_load
            const float bias = b1g[c];
            float acc = 0.f;
            #pragma unroll
            for (int rr = 0; rr < 2; rr++)
                #pragma unroll
                for (int cc = 0; cc < 2; cc++) {
                    float v = bias;
                    #pragma unroll
                    for (int i = 0; i < 3; i++)
                        #pragma unroll
                        for (int j = 0; j < 3; j++)
                            v += p[rr + i][cc + j] * w[i * 3 + j];
                    acc += fmaxf(v, 0.f);
                }
            res[c] = 0.25f * acc;
        }
        const int slot = (x >> 1) + 5 * (x & 1);
        h4 lo = { (half_t)res[0], (half_t)res[1], (half_t)res[2], (half_t)res[3] };
        h4 hi = { (half_t)res[4], (half_t)res[5], (half_t)res[6], (half_t)res[7] };
        *(h4*)&s_p1n[img][0][y][slot][0] = lo;
        *(h4*)&s_p1n[img][1][y][slot][0] = hi;
    }
    __syncthreads();

    const int img2 = tid >> 6;          // wave = image
    const int t6   = tid & 63;

    // ---- stage 2: conv2(8->16)+relu+pool2; thread=(img, pos, oc-quad); dot2 fp16.
    {
        const int pos = t6 >> 2;        // 0..15 pooled position
        const int q   = t6 & 3;         // oc quad
        const int y   = pos >> 2, x = pos & 3;
        const int r0  = 2 * y;
        const int slotm[4] = { x, 5 + x, x + 1, 6 + x };
        float v[4][4];
        #pragma unroll
        for (int oc = 0; oc < 4; oc++) {
            const float bias = b2g[q * 4 + oc];
            #pragma unroll
            for (int w2 = 0; w2 < 4; w2++) v[oc][w2] = bias;
        }
        #pragma unroll
        for (int g = 0; g < 2; g++) {
            h2 aL[4][4], aH[4][4];
            #pragma unroll
            for (int i = 0; i < 4; i++)
                #pragma unroll
                for (int dx = 0; dx < 4; dx++) {
                    h4 a = *(const h4*)&s_p1n[img2][g][r0 + i][slotm[dx]][0];
                    aL[i][dx] = __builtin_shufflevector(a, a, 0, 1);
                    aH[i][dx] = __builtin_shufflevector(a, a, 2, 3);
                }
            #pragma unroll
            for (int k = 0; k < 9; k++) {
                const int di = k / 3, dj = k - di * 3;
                #pragma unroll
                for (int oc = 0; oc < 4; oc++) {
                    h4 w = *(const h4*)&w2h[((k * 2 + g) * 16 + q * 4 + oc) * 4];
                    h2 wL = __builtin_shufflevector(w, w, 0, 1);
                    h2 wH = __builtin_shufflevector(w, w, 2, 3);
                    #pragma unroll
                    for (int rr = 0; rr < 2; rr++)
                        #pragma unroll
                        for (int cc = 0; cc < 2; cc++) {
                            float* acc = &v[oc][rr * 2 + cc];
                            *acc = fdot2f(aL[rr + di][cc + dj], wL, *acc);
                            *acc = fdot2f(aH[rr + di][cc + dj], wH, *acc);
                        }
                }
            }
        }
        float res[4];
        #pragma unroll
        for (int oc = 0; oc < 4; oc++)
            res[oc] = 0.25f * (fmaxf(v[oc][0], 0.f) + fmaxf(v[oc][1], 0.f) +
                               fmaxf(v[oc][2], 0.f) + fmaxf(v[oc][3], 0.f));
        h4 o = { (half_t)res[0], (half_t)res[1], (half_t)res[2], (half_t)res[3] };
        *(h4*)&s_p2n[img2][pos][q * 4] = o;
    }
    __syncthreads();

    // ---- stage 3: conv3(16->32)+relu; thread=(img, c, u) computes windows v=0,1; dot2 fp16.
    {
        const int c = t6 >> 1;
        const int u = t6 & 1;
        float acc0 = b3g[c], acc1 = acc0;
        #pragma unroll
        for (int g = 0; g < 4; g++) {
            h2 AL[3][4], AH[3][4];
            #pragma unroll
            for (int i = 0; i < 3; i++)
                #pragma unroll
                for (int jj = 0; jj < 4; jj++) {
                    h4 a = *(const h4*)&s_p2n[img2][(u + i) * 4 + jj][g * 4];
                    AL[i][jj] = __builtin_shufflevector(a, a, 0, 1);
                    AH[i][jj] = __builtin_shufflevector(a, a, 2, 3);
                }
            #pragma unroll
            for (int i = 0; i < 3; i++)
                #pragma unroll
                for (int j = 0; j < 3; j++) {
                    const int k = i * 3 + j;
                    h4 w = *(const h4*)&w3h[((k * 4 + g) * 32 + c) * 4];
                    h2 wL = __builtin_shufflevector(w, w, 0, 1);
                    h2 wH = __builtin_shufflevector(w, w, 2, 3);
                    acc0 = fdot2f(AL[i][j], wL, acc0);
                    acc0 = fdot2f(AH[i][j], wH, acc0);
                    acc1 = fdot2f(AL[i][j + 1], wL, acc1);
                    acc1 = fdot2f(AH[i][j + 1], wH, acc1);
                }
        }
        s_c3[img2][c][u * 2 + 0] = fmaxf(acc0, 0.f);
        s_c3[img2][c][u * 2 + 1] = fmaxf(acc1, 0.f);
    }
    __syncthreads();
    if (t6 < 32)
        s_p3[img2][t6] = 0.25f * (s_c3[img2][t6][0] + s_c3[img2][t6][1] +
                                  s_c3[img2][t6][2] + s_c3[img2][t6][3]);
    __syncthreads();

    // ---- dense + softmax + guards (per wave = per image), fp32
    if (t6 < 10) {
        float acc = bdg[t6];
        #pragma unroll
        for (int c2 = 0; c2 < 32; c2++) acc += s_p3[img2][c2] * wdt[c2 * 10 + t6];
        s_logit[img2][t6] = acc;
    }
    __syncthreads();
    if (t6 < 10) {
        const int m = mbase + img2;
        float mx = s_logit[img2][0];
        #pragma unroll
        for (int k = 1; k < 10; k++) mx = fmaxf(mx, s_logit[img2][k]);
        float ssum = 0.f;
        #pragma unroll
        for (int k = 0; k < 10; k++) ssum += __expf(s_logit[img2][k] - mx);
        float p = __expf(s_logit[img2][t6] - mx) / ssum;
        s_prob[img2][t6] = p;
        out[(size_t)m * 10 + t6] = p;                  // all_cnn_preds (N,B,10)
    }
    __syncthreads();
    if (t6 < 6) {
        const int m = mbase + img2;
        // rules: [p8, p4+p6, p0+p2, p7+p9, p5, p1+p3]
        int ia = (0x157048 >> (t6 * 4)) & 0xF;
        int ib = (0x3F926F >> (t6 * 4)) & 0xF;
        float gv = s_prob[img2][ia] + (ib < 10 ? s_prob[img2][ib] : 0.f);
        out[81920 + (size_t)m * 6 + t6] = gv;          // all_guard_preds (N,B,6)
        g_ws[(size_t)m * 6 + t6] = gv;                 // scratch for recurrence
    }
}

// 11 blocks x 256 threads. lane = bb*10 + j inside a wave (6 batches/wave).
// M column in 54 registers; state exchange via __shfl — zero barriers in the loop.
__global__ __launch_bounds__(256) void sfa_kernel(
    const float* __restrict__ trans,
    const float* __restrict__ g_ws,
    float* __restrict__ out)
{
    __shared__ float M[600];           // [r][i][j]
    const int tid  = threadIdx.x;
    const int lane = tid & 63;
    const int wv   = tid >> 6;

    if (tid < 54) {
        int r = tid / 9, i = tid - r * 9;
        const float* row = trans + (size_t)(r * 9 + i) * 10;
        float x[10], mx = -1e30f;
        #pragma unroll
        for (int j = 0; j < 10; j++) { x[j] = 10.f * row[j]; mx = fmaxf(mx, x[j]); }
        float s = 0.f;
        #pragma unroll
        for (int j = 0; j < 10; j++) { x[j] = __expf(x[j] - mx); s += x[j]; }
        float inv = 1.f / s;
        #pragma unroll
        for (int j = 0; j < 10; j++) M[(r * 9 + i) * 10 + j] = x[j] * inv;
    }
    __syncthreads();

    const int bb    = lane / 10;                    // batch-in-wave, 0..6 (6 invalid)
    const int j     = lane - bb * 10;
    const int base  = bb * 10;
    const bool ok   = (bb < 6);
    int batch = blockIdx.x * 24 + wv * 6 + bb;
    const bool live = ok && (batch < 256);
    if (!live) batch = 0;

    float Mreg[54];
    #pragma unroll
    for (int k = 0; k < 54; k++) Mreg[k] = M[k * 10 + j];

    float stj = (j == 0) ? 1.f : 0.f;

    for (int nn = 0; nn < 32; nn++) {
        const float* gp = g_ws + ((size_t)nn * 256 + batch) * 6;
        float2 ga = *(const float2*)(gp);
        float2 gb = *(const float2*)(gp + 2);
        float2 gc = *(const float2*)(gp + 4);
        float g[6] = {ga.x, ga.y, gb.x, gb.y, gc.x, gc.y};

        float st[10];
        #pragma unroll
        for (int i = 0; i < 10; i++) st[i] = __shfl(stj, base + i, 64);

        float gsum = g[0] + g[1] + g[2] + g[3] + g[4] + g[5];
        float ns = (j == 9) ? gsum * st[9] : 0.f;   // accepting row
        #pragma unroll
        for (int r = 0; r < 6; r++) {
            float h = 0.f;
            #pragma unroll
            for (int i = 0; i < 9; i++) h += st[i] * Mreg[r * 9 + i];
            ns += g[r] * h;
        }
        stj = ns;
    }
    if (live) out[131072 + (size_t)batch * 10 + j] = stj;   // state_final (B,10)
}

extern "C" void kernel_launch(void* const* d_in, const int* in_sizes, int n_in,
                              void* d_out, int out_size, void* d_ws, size_t ws_size,
                              hipStream_t stream) {
    const float* seq = (const float*)d_in[0];
    const float* w1  = (const float*)d_in[1];
    const float* b1  = (const float*)d_in[2];
    const float* w2  = (const float*)d_in[3];
    const float* b2  = (const float*)d_in[4];
    const float* w3  = (const float*)d_in[5];
    const float* b3  = (const float*)d_in[6];
    const float* wd  = (const float*)d_in[7];
    const float* bd  = (const float*)d_in[8];
    const float* tr  = (const float*)d_in[9];
    float* out  = (float*)d_out;
    float* g_ws = (float*)d_ws;            // [0, 49152) floats: guard probs scratch
    float* wsW  = g_ws + 49152;            // wdt fp32 [0,320) + w2h/w3h fp16

    prep_kernel<<<1, 256, 0, stream>>>(w2, w3, wd, wsW);
    cnn_kernel<<<2048, 256, 0, stream>>>(seq, w1, b1, b2, b3, bd, wsW, out, g_ws);
    sfa_kernel<<<11, 256, 0, stream>>>(tr, g_ws, out);
}

// Round 10
// 138.641 us; speedup vs baseline: 3.0548x; 1.0729x over previous
//
#include <hip/hip_runtime.h>

typedef _Float16 half_t;
typedef _Float16 h2 __attribute__((ext_vector_type(2)));
typedef _Float16 h4 __attribute__((ext_vector_type(4)));

__device__ __forceinline__ float fdot2f(h2 a, h2 b, float c) {
#if __has_builtin(__builtin_amdgcn_fdot2)
    return __builtin_amdgcn_fdot2(a, b, c, false);
#else
    return c + (float)a.x * (float)b.x + (float)a.y * (float)b.y;
#endif
}

// ---- prep: weights -> ws once. Layout: wdt fp32 [0,320) ; w2h half ; w3h after.
__global__ __launch_bounds__(256) void prep_kernel(
    const float* __restrict__ w2g, const float* __restrict__ w3g,
    const float* __restrict__ wdg, float* __restrict__ wsW)
{
    const int tid = threadIdx.x;
    half_t* w2h = (half_t*)(wsW + 320);
    half_t* w3h = w2h + 1152;
    for (int i = tid; i < 320; i += 256) {             // wdt[c2*10+j] = wd[j][c2]
        int j = i >> 5, c2 = i & 31;
        wsW[c2 * 10 + j] = wdg[i];
    }
    for (int i = tid; i < 1152; i += 256) {            // w2h[((k*2+g)*16+c)*4+l] = w2[c][g*4+l][k]
        int l = i & 3, c = (i >> 2) & 15, g = (i >> 6) & 1, k = i >> 7;
        w2h[i] = (half_t)w2g[(c * 8 + g * 4 + l) * 9 + k];
    }
    for (int i = tid; i < 4608; i += 256) {            // w3h[((k*4+g)*32+c)*4+l] = w3[c][g*4+l][k]
        int l = i & 3, c = (i >> 2) & 31, g = (i >> 7) & 3, k = i >> 9;
        w3h[i] = (half_t)w3g[(c * 16 + g * 4 + l) * 9 + k];
    }
}

// 4 images per block (grid 2048), 256 threads; wave = image for stages 2/3.
// fp32 image, fp16 acts, dot2 stages 2/3 with hoisted weight regs, shfl epilogue.
__global__ __launch_bounds__(256, 6) void cnn_kernel(
    const float* __restrict__ seq,
    const float* __restrict__ w1g, const float* __restrict__ b1g,
    const float* __restrict__ b2g, const float* __restrict__ b3g,
    const float* __restrict__ bdg, const float* __restrict__ wsW,
    float* __restrict__ out, float* __restrict__ g_ws)
{
    __shared__ __align__(16) float  s_img2[4][28][28];      // parity: [0..13]=even, [14..27]=odd
    __shared__ __align__(16) half_t s_p1n[4][2][10][11][4]; // [img][g][y][slot][l]; ic=g*4+l
    __shared__ __align__(16) half_t s_p2n[4][16][16];       // [img][pixel(y*4+x)][16 ic]
    __shared__ float s_p3[4][32];

    const int tid   = threadIdx.x;
    const int mbase = blockIdx.x * 4;
    const float*  wdt = wsW;
    const half_t* w2h = (const half_t*)(wsW + 320);
    const half_t* w3h = w2h + 1152;

    // ---- stage images (parity de-interleave, fp32)
    if (tid < 196) {
        #pragma unroll
        for (int img = 0; img < 4; img++) {
            const int m = mbase + img;
            const int b = m & 255, nn = m >> 8;
            const int t = nn >> 2, dd = nn & 3;
            const float4* s4 = (const float4*)(seq + (((size_t)b * 8 + t) * 4 + dd) * 784);
            float4 v = s4[tid];
            int flat = tid * 4;
            int r  = flat / 28;
            int cb = flat - r * 28;       // multiple of 4
            int e  = cb >> 1;
            *(float2*)&s_img2[img][r][e]      = make_float2(v.x, v.z);
            *(float2*)&s_img2[img][r][14 + e] = make_float2(v.y, v.w);
        }
    }
    __syncthreads();

    // ---- stage 1: conv1(1->8)+relu+pool2 at the 100 needed positions/image (400 items).
    for (int idx = tid; idx < 400; idx += 256) {
        const int img = idx / 100;
        const int rem = idx - img * 100;
        const int y   = rem / 10;
        const int x   = rem - y * 10;
        const int r0  = 2 * y;
        float p[4][4];
        #pragma unroll
        for (int i = 0; i < 4; i++) {
            const float* rp = &s_img2[img][r0 + i][0];
            p[i][0] = rp[x];
            p[i][1] = rp[14 + x];
            p[i][2] = rp[x + 1];
            p[i][3] = rp[15 + x];
        }
        float res[8];
        #pragma unroll
        for (int c = 0; c < 8; c++) {
            float w[9];
            #pragma unroll
            for (int k = 0; k < 9; k++) w[k] = w1g[c * 9 + k];   // uniform -> s_load
            const float bias = b1g[c];
            float acc = 0.f;
            #pragma unroll
            for (int rr = 0; rr < 2; rr++)
                #pragma unroll
                for (int cc = 0; cc < 2; cc++) {
                    float v = bias;
                    #pragma unroll
                    for (int i = 0; i < 3; i++)
                        #pragma unroll
                        for (int j = 0; j < 3; j++)
                            v += p[rr + i][cc + j] * w[i * 3 + j];
                    acc += fmaxf(v, 0.f);
                }
            res[c] = 0.25f * acc;
        }
        const int slot = (x >> 1) + 5 * (x & 1);
        h4 lo = { (half_t)res[0], (half_t)res[1], (half_t)res[2], (half_t)res[3] };
        h4 hi = { (half_t)res[4], (half_t)res[5], (half_t)res[6], (half_t)res[7] };
        *(h4*)&s_p1n[img][0][y][slot][0] = lo;
        *(h4*)&s_p1n[img][1][y][slot][0] = hi;
    }
    __syncthreads();

    const int img2 = tid >> 6;          // wave = image
    const int t6   = tid & 63;

    // ---- stage 2: conv2(8->16)+relu+pool2; thread=(img,pos,oc-quad); weights hoisted per (g,oc).
    {
        const int pos = t6 >> 2;
        const int q   = t6 & 3;
        const int y   = pos >> 2, x = pos & 3;
        const int r0  = 2 * y;
        const int slotm[4] = { x, 5 + x, x + 1, 6 + x };
        float v[4][4];
        #pragma unroll
        for (int oc = 0; oc < 4; oc++) {
            const float bias = b2g[q * 4 + oc];
            #pragma unroll
            for (int w2 = 0; w2 < 4; w2++) v[oc][w2] = bias;
        }
        #pragma unroll
        for (int g = 0; g < 2; g++) {
            h2 aL[4][4], aH[4][4];
            #pragma unroll
            for (int i = 0; i < 4; i++)
                #pragma unroll
                for (int dx = 0; dx < 4; dx++) {
                    h4 a = *(const h4*)&s_p1n[img2][g][r0 + i][slotm[dx]][0];
                    aL[i][dx] = __builtin_shufflevector(a, a, 0, 1);
                    aH[i][dx] = __builtin_shufflevector(a, a, 2, 3);
                }
            #pragma unroll
            for (int oc = 0; oc < 4; oc++) {
                h4 wk[9];
                #pragma unroll
                for (int k = 0; k < 9; k++)
                    wk[k] = *(const h4*)&w2h[((k * 2 + g) * 16 + q * 4 + oc) * 4];
                #pragma unroll
                for (int k = 0; k < 9; k++) {
                    const int di = k / 3, dj = k - di * 3;
                    h2 wL = __builtin_shufflevector(wk[k], wk[k], 0, 1);
                    h2 wH = __builtin_shufflevector(wk[k], wk[k], 2, 3);
                    #pragma unroll
                    for (int rr = 0; rr < 2; rr++)
                        #pragma unroll
                        for (int cc = 0; cc < 2; cc++) {
                            float* acc = &v[oc][rr * 2 + cc];
                            *acc = fdot2f(aL[rr + di][cc + dj], wL, *acc);
                            *acc = fdot2f(aH[rr + di][cc + dj], wH, *acc);
                        }
                }
            }
        }
        float res[4];
        #pragma unroll
        for (int oc = 0; oc < 4; oc++)
            res[oc] = 0.25f * (fmaxf(v[oc][0], 0.f) + fmaxf(v[oc][1], 0.f) +
                               fmaxf(v[oc][2], 0.f) + fmaxf(v[oc][3], 0.f));
        h4 o = { (half_t)res[0], (half_t)res[1], (half_t)res[2], (half_t)res[3] };
        *(h4*)&s_p2n[img2][pos][q * 4] = o;
    }
    __syncthreads();

    // ---- stage 3: conv3(16->32)+relu; thread=(img,c,u), windows v=0,1; shfl pool.
    {
        const int c = t6 >> 1;
        const int u = t6 & 1;
        float acc0 = b3g[c], acc1 = acc0;
        #pragma unroll
        for (int g = 0; g < 4; g++) {
            h2 AL[3][4], AH[3][4];
            #pragma unroll
            for (int i = 0; i < 3; i++)
                #pragma unroll
                for (int jj = 0; jj < 4; jj++) {
                    h4 a = *(const h4*)&s_p2n[img2][(u + i) * 4 + jj][g * 4];
                    AL[i][jj] = __builtin_shufflevector(a, a, 0, 1);
                    AH[i][jj] = __builtin_shufflevector(a, a, 2, 3);
                }
            h4 wk[9];
            #pragma unroll
            for (int k = 0; k < 9; k++)
                wk[k] = *(const h4*)&w3h[((k * 4 + g) * 32 + c) * 4];
            #pragma unroll
            for (int k = 0; k < 9; k++) {
                const int i = k / 3, j = k - i * 3;
                h2 wL = __builtin_shufflevector(wk[k], wk[k], 0, 1);
                h2 wH = __builtin_shufflevector(wk[k], wk[k], 2, 3);
                acc0 = fdot2f(AL[i][j], wL, acc0);
                acc0 = fdot2f(AH[i][j], wH, acc0);
                acc1 = fdot2f(AL[i][j + 1], wL, acc1);
                acc1 = fdot2f(AH[i][j + 1], wH, acc1);
            }
        }
        float s = fmaxf(acc0, 0.f) + fmaxf(acc1, 0.f);
        s += __shfl_xor(s, 1, 64);                 // partner u^1
        if (u == 0) s_p3[img2][c] = 0.25f * s;     // lane c -> bank c, conflict-free
    }
    __syncthreads();

    // ---- dense + shfl softmax + guards (no more barriers)
    {
        float logit = -1e30f;
        if (t6 < 10) {
            float acc = bdg[t6];
            #pragma unroll
            for (int c2 = 0; c2 < 32; c2++) acc += s_p3[img2][c2] * wdt[c2 * 10 + t6];
            logit = acc;
        }
        float mx = logit;
        #pragma unroll
        for (int s = 1; s < 16; s <<= 1) mx = fmaxf(mx, __shfl_xor(mx, s, 16));
        float e = (t6 < 10) ? __expf(logit - mx) : 0.f;
        float ssum = e;
        #pragma unroll
        for (int s = 1; s < 16; s <<= 1) ssum += __shfl_xor(ssum, s, 16);
        float p = e / ssum;                        // lanes 10..15 -> p = 0
        const int m = mbase + img2;
        if (t6 < 10) out[(size_t)m * 10 + t6] = p; // all_cnn_preds (N,B,10)

        // guards: [p8, p4+p6, p0+p2, p7+p9, p5, p1+p3]; 0xF slot reads lane 15 (p=0)
        const int sh = (t6 < 6 ? t6 : 0) * 4;
        const int ia = (0x157048 >> sh) & 0xF;
        const int ib = (0x3F926F >> sh) & 0xF;
        float pa = __shfl(p, ia, 16);
        float pb = __shfl(p, ib, 16);
        if (t6 < 6) {
            float gv = pa + pb;
            out[81920 + (size_t)m * 6 + t6] = gv;  // all_guard_preds (N,B,6)
            g_ws[(size_t)m * 6 + t6] = gv;         // scratch for recurrence
        }
    }
}

// 11 blocks x 256 threads. lane = bb*10 + j inside a wave (6 batches/wave).
// M column in 54 registers; state exchange via __shfl — zero barriers in the loop.
__global__ __launch_bounds__(256) void sfa_kernel(
    const float* __restrict__ trans,
    const float* __restrict__ g_ws,
    float* __restrict__ out)
{
    __shared__ float M[600];           // [r][i][j]
    const int tid  = threadIdx.x;
    const int lane = tid & 63;
    const int wv   = tid >> 6;

    if (tid < 54) {
        int r = tid / 9, i = tid - r * 9;
        const float* row = trans + (size_t)(r * 9 + i) * 10;
        float x[10], mx = -1e30f;
        #pragma unroll
        for (int j = 0; j < 10; j++) { x[j] = 10.f * row[j]; mx = fmaxf(mx, x[j]); }
        float s = 0.f;
        #pragma unroll
        for (int j = 0; j < 10; j++) { x[j] = __expf(x[j] - mx); s += x[j]; }
        float inv = 1.f / s;
        #pragma unroll
        for (int j = 0; j < 10; j++) M[(r * 9 + i) * 10 + j] = x[j] * inv;
    }
    __syncthreads();

    const int bb    = lane / 10;                    // batch-in-wave, 0..6 (6 invalid)
    const int j     = lane - bb * 10;
    const int base  = bb * 10;
    const bool ok   = (bb < 6);
    int batch = blockIdx.x * 24 + wv * 6 + bb;
    const bool live = ok && (batch < 256);
    if (!live) batch = 0;

    float Mreg[54];
    #pragma unroll
    for (int k = 0; k < 54; k++) Mreg[k] = M[k * 10 + j];

    float stj = (j == 0) ? 1.f : 0.f;

    for (int nn = 0; nn < 32; nn++) {
        const float* gp = g_ws + ((size_t)nn * 256 + batch) * 6;
        float2 ga = *(const float2*)(gp);
        float2 gb = *(const float2*)(gp + 2);
        float2 gc = *(const float2*)(gp + 4);
        float g[6] = {ga.x, ga.y, gb.x, gb.y, gc.x, gc.y};

        float st[10];
        #pragma unroll
        for (int i = 0; i < 10; i++) st[i] = __shfl(stj, base + i, 64);

        float gsum = g[0] + g[1] + g[2] + g[3] + g[4] + g[5];
        float ns = (j == 9) ? gsum * st[9] : 0.f;   // accepting row
        #pragma unroll
        for (int r = 0; r < 6; r++) {
            float h = 0.f;
            #pragma unroll
            for (int i = 0; i < 9; i++) h += st[i] * Mreg[r * 9 + i];
            ns += g[r] * h;
        }
        stj = ns;
    }
    if (live) out[131072 + (size_t)batch * 10 + j] = stj;   // state_final (B,10)
}

extern "C" void kernel_launch(void* const* d_in, const int* in_sizes, int n_in,
                              void* d_out, int out_size, void* d_ws, size_t ws_size,
                              hipStream_t stream) {
    const float* seq = (const float*)d_in[0];
    const float* w1  = (const float*)d_in[1];
    const float* b1  = (const float*)d_in[2];
    const float* w2  = (const float*)d_in[3];
    const float* b2  = (const float*)d_in[4];
    const float* w3  = (const float*)d_in[5];
    const float* b3  = (const float*)d_in[6];
    const float* wd  = (const float*)d_in[7];
    const float* bd  = (const float*)d_in[8];
    const float* tr  = (const float*)d_in[9];
    float* out  = (float*)d_out;
    float* g_ws = (float*)d_ws;            // [0, 49152) floats: guard probs scratch
    float* wsW  = g_ws + 49152;            // wdt fp32 [0,320) + w2h/w3h fp16

    prep_kernel<<<1, 256, 0, stream>>>(w2, w3, wd, wsW);
    cnn_kernel<<<2048, 256, 0, stream>>>(seq, w1, b1, b2, b3, bd, wsW, out, g_ws);
    sfa_kernel<<<11, 256, 0, stream>>>(tr, g_ws, out);
}